// Round 5
// baseline (1045.772 us; speedup 1.0000x reference)
//
#include <hip/hip_runtime.h>
#include <math.h>

#define B_   8
#define C_   96
#define C2_  192
#define N_   3136        // 56*56
#define R_   25088       // B_*N_
#define OUP_ 192
#define HO_  28
#define NO_  784         // 28*28
#define EPS_ 1e-5f
#define PSTR 200         // padded split-bf16 point stride (elements)
#define DSTR 68          // dist LDS key tile stride (u32), 68 % 32 == 4 -> 2-way max
#define CAP_ 64          // per-row candidate pool cap

typedef short bf16x8 __attribute__((ext_vector_type(8)));
typedef float f32x4  __attribute__((ext_vector_type(4)));

// generic strict-< sorted insertion (static unroll)
#define INSERTK(K, kd, ki, dv, iv, T)                                       \
    if ((dv) < kd[(K)-1]) {                                                 \
        kd[(K)-1] = (dv); ki[(K)-1] = (iv);                                 \
        _Pragma("unroll")                                                   \
        for (int j = (K)-1; j >= 1; --j) {                                  \
            if (kd[j] < kd[j - 1]) {                                        \
                T td = kd[j]; kd[j] = kd[j - 1]; kd[j - 1] = td;            \
                int ti = ki[j]; ki[j] = ki[j - 1]; ki[j - 1] = ti;          \
            }                                                               \
        }                                                                   \
    }

// ---------------- fc1 (fp64 accumulate): yd[b,d,n] = sum_c x[b,c,n]*W1[c,d] + b1[d] ----------------
__global__ __launch_bounds__(512) void k_fc1_d(const float* __restrict__ x,
                                               const float* __restrict__ W1,
                                               const float* __restrict__ b1,
                                               double* __restrict__ yd) {
    __shared__ double Wl[96 * 48];
    int tid = threadIdx.x;
    int rl = tid & 255, h = tid >> 8;
    int dbase = blockIdx.y * 48;
    for (int q = tid; q < 96 * 48; q += 512) {
        int c = q / 48, dd = q % 48;
        Wl[c * 48 + dd] = (double)W1[c * 96 + dbase + dd];
    }
    __syncthreads();
    int r = blockIdx.x * 256 + rl;
    int b = r / N_;
    int n = r - b * N_;
    double acc[24];
#pragma unroll
    for (int i = 0; i < 24; i++) acc[i] = 0.0;
    const float* xp = x + (size_t)b * C_ * N_ + n;
    for (int c = 0; c < 96; ++c) {
        double xv = (double)xp[(size_t)c * N_];
        const double* w = &Wl[c * 48 + h * 24];
#pragma unroll
        for (int i = 0; i < 24; ++i) acc[i] += xv * w[i];
    }
    int d0 = dbase + h * 24;
#pragma unroll
    for (int i = 0; i < 24; i++) {
        int d = d0 + i;
        yd[((size_t)b * C_ + d) * N_ + n] = acc[i] + (double)b1[d];
    }
}

// ---------------- fp64 per-channel stats over yd ----------------
__global__ __launch_bounds__(256) void k_stats_chan_d(const double* __restrict__ src,
                                                      double* __restrict__ partial) {
    int c = blockIdx.x;
    int chunk = blockIdx.y;
    const int SPLIT = 16;
    double s = 0.0, ss = 0.0;
    for (int j = chunk * 256 + threadIdx.x; j < R_; j += SPLIT * 256) {
        int b = j / N_, n = j - b * N_;
        double v = src[((size_t)b * C_ + c) * N_ + n];
        s += v;
        ss += v * v;
    }
    __shared__ double red[8];
    for (int off = 32; off; off >>= 1) {
        s += __shfl_down(s, off, 64);
        ss += __shfl_down(ss, off, 64);
    }
    int lane = threadIdx.x & 63, w = threadIdx.x >> 6;
    if (lane == 0) { red[w * 2] = s; red[w * 2 + 1] = ss; }
    __syncthreads();
    if (threadIdx.x == 0) {
        s = red[0] + red[2] + red[4] + red[6];
        ss = red[1] + red[3] + red[5] + red[7];
        partial[(c * SPLIT + chunk) * 2] = s;
        partial[(c * SPLIT + chunk) * 2 + 1] = ss;
    }
}

__global__ void k_stats_reduce_d(const double* __restrict__ partial, double* __restrict__ stats) {
    int c = blockIdx.x * blockDim.x + threadIdx.x;
    if (c >= 96) return;
    double s = 0.0, ss = 0.0;
    for (int k = 0; k < 16; k++) {
        s += partial[(c * 16 + k) * 2];
        ss += partial[(c * 16 + k) * 2 + 1];
    }
    double m = s / (double)R_;
    double var = ss / (double)R_ - m * m;
    stats[c * 2] = m;
    stats[c * 2 + 1] = 1.0 / sqrt(var + 1e-5);
}

// ---------------- fp32 per-channel stats ----------------
__global__ __launch_bounds__(256) void k_stats_chan(const float* __restrict__ src,
                                                    float* __restrict__ partial,
                                                    int Cn, int Nsp, int total) {
    int c = blockIdx.x;
    int chunk = blockIdx.y;
    int SPLIT = gridDim.y;
    float s = 0.f, ss = 0.f;
    for (int j = chunk * 256 + threadIdx.x; j < total; j += SPLIT * 256) {
        int b = j / Nsp, n = j - b * Nsp;
        float v = src[((size_t)b * Cn + c) * Nsp + n];
        s += v;
        ss += v * v;
    }
    __shared__ float red[8];
    for (int off = 32; off; off >>= 1) {
        s += __shfl_down(s, off, 64);
        ss += __shfl_down(ss, off, 64);
    }
    int lane = threadIdx.x & 63, w = threadIdx.x >> 6;
    if (lane == 0) { red[w * 2] = s; red[w * 2 + 1] = ss; }
    __syncthreads();
    if (threadIdx.x == 0) {
        s = red[0] + red[2] + red[4] + red[6];
        ss = red[1] + red[3] + red[5] + red[7];
        partial[(c * SPLIT + chunk) * 2] = s;
        partial[(c * SPLIT + chunk) * 2 + 1] = ss;
    }
}

__global__ void k_stats_reduce(const float* __restrict__ partial, float* __restrict__ stats,
                               int Cn, int SPLIT, float invcount) {
    int c = blockIdx.x * blockDim.x + threadIdx.x;
    if (c >= Cn) return;
    float s = 0.f, ss = 0.f;
    for (int k = 0; k < SPLIT; k++) {
        s += partial[(c * SPLIT + k) * 2];
        ss += partial[(c * SPLIT + k) * 2 + 1];
    }
    float m = s * invcount;
    float var = ss * invcount - m * m;
    stats[c * 2] = m;
    stats[c * 2 + 1] = 1.0f / sqrtf(var + EPS_);
}

// parallel reduce for k_bne_stats partials: one block per channel
__global__ __launch_bounds__(256) void k_stats_reduce_b2(const float* __restrict__ partial,
                                                         float* __restrict__ stats,
                                                         float invcount) {
    int c = blockIdx.x;      // 0..191
    float s = 0.f, ss = 0.f;
    for (int k = threadIdx.x; k < 784; k += 256) {
        s  += partial[(size_t)k * 384 + c];
        ss += partial[(size_t)k * 384 + 192 + c];
    }
    __shared__ float red[8];
    for (int off = 32; off; off >>= 1) {
        s += __shfl_down(s, off, 64);
        ss += __shfl_down(ss, off, 64);
    }
    int lane = threadIdx.x & 63, w = threadIdx.x >> 6;
    if (lane == 0) { red[w * 2] = s; red[w * 2 + 1] = ss; }
    __syncthreads();
    if (threadIdx.x == 0) {
        s = red[0] + red[2] + red[4] + red[6];
        ss = red[1] + red[3] + red[5] + red[7];
        float m = s * invcount;
        float var = ss * invcount - m * m;
        stats[c * 2] = m;
        stats[c * 2 + 1] = 1.0f / sqrtf(var + EPS_);
    }
}

// ---------------- apply BN1 (fp64); emit ftc (f32 ch-major), ftp32/ftp64 (point-major) ----------------
__global__ __launch_bounds__(256) void k_bn1_apply_d(const double* __restrict__ yd,
                                                     const double* __restrict__ stats,
                                                     const float* __restrict__ g,
                                                     const float* __restrict__ be,
                                                     float* __restrict__ ftc,
                                                     float* __restrict__ ftp32,
                                                     double* __restrict__ ftp64) {
    int i = blockIdx.x * 256 + threadIdx.x;
    if (i >= B_ * C_ * N_) return;
    int n = i % N_;
    int bc = i / N_;
    int c = bc % C_;
    int b = bc / C_;
    double m = stats[c * 2], rs = stats[c * 2 + 1];
    double v = (double)g[c] * (yd[i] - m) * rs + (double)be[c];
    float vf = (float)v;
    ftc[i] = vf;
    size_t pp = ((size_t)b * N_ + n) * C_ + c;
    ftp32[pp] = vf;
    ftp64[pp] = v;
}

// ---------------- row squared norms: fp64 exact + fp32 copy ----------------
__global__ __launch_bounds__(256) void k_sqrows_d(const double* __restrict__ ftp64,
                                                  double* __restrict__ sq64,
                                                  float* __restrict__ sq32) {
    int r = blockIdx.x * 256 + threadIdx.x;
    if (r >= R_) return;
    const double* p = ftp64 + (size_t)r * C_;
    double s = 0.0;
    for (int q = 0; q < 96; q++) s += p[q] * p[q];
    sq64[r] = s;
    sq32[r] = (float)s;
}

// ---------------- split ft into bf16 hi/lo pairs (point-major, padded stride) ----------------
__global__ __launch_bounds__(256) void k_split(const float* __restrict__ ftp32,
                                               unsigned short* __restrict__ fsp) {
    int t = blockIdx.x * 256 + threadIdx.x;
    if (t >= R_ * 12) return;
    int p = t / 12, g = t % 12;
    const float* src = ftp32 + (size_t)p * C_ + g * 8;
    unsigned short hi[8], lo[8];
#pragma unroll
    for (int j = 0; j < 8; ++j) {
        float x = src[j];
        unsigned u = __float_as_uint(x);
        unsigned r = (u + 0x7fffu + ((u >> 16) & 1u)) >> 16;       // RNE to bf16
        float hf = __uint_as_float(r << 16);
        hi[j] = (unsigned short)r;
        float res = x - hf;                                        // exact
        unsigned u2 = __float_as_uint(res);
        unsigned r2 = (u2 + 0x7fffu + ((u2 >> 16) & 1u)) >> 16;
        lo[j] = (unsigned short)r2;
    }
    unsigned short* dh = fsp + (size_t)p * PSTR + g * 8;
    unsigned short* dl = dh + 96;
    *(ushort4*)dh       = *(ushort4*)&hi[0];
    *(ushort4*)(dh + 4) = *(ushort4*)&hi[4];
    *(ushort4*)dl       = *(ushort4*)&lo[0];
    *(ushort4*)(dl + 4) = *(ushort4*)&lo[4];
}

// ---------------- split-bf16 MFMA distance, two-pass threshold + compaction ----------------
// block: 32 query rows x all 3136 candidates (49 chunks of 64), 4 waves.
// key = monotone-u32(dist - sqn)[20 bits] | global-col[12 bits]
// pass 0: per-row chunk minima -> t16 = 16th-smallest chunk-min (upper bound of true 16th)
// pass 1: compact all keys <= t16 into per-row pool (>=16 guaranteed; expected ~25)
__global__ __launch_bounds__(256) void k_dist_mfma(const unsigned short* __restrict__ fsp,
                                                   const float* __restrict__ sq32,
                                                   unsigned* __restrict__ poolK,
                                                   unsigned* __restrict__ poolCnt) {
    __shared__ __align__(16) char lds[50688];
    unsigned short* Al   = (unsigned short*)lds;             // [0,12800) staging (dead after frag load)
    unsigned*       pool = (unsigned*)lds;                   // 32x64 u32 = 8192 (aliases Al)
    unsigned*       cnt  = (unsigned*)(lds + 8192);          // 32 u32
    unsigned short* Bl   = (unsigned short*)(lds + 12800);   // 64x200 u16 = 25600
    unsigned*       distl= (unsigned*)(lds + 38400);         // 32x68 u32 = 8704
    unsigned short* cmin = (unsigned short*)(lds + 47104);   // 32x50 u16 = 3200
    unsigned short* t16l = (unsigned short*)(lds + 50304);   // 32 u16
    float*          sqtl = (float*)(lds + 50368);            // 64 f32 -> ends 50624

    int b = blockIdx.y;
    int r0 = blockIdx.x * 32;
    int tid = threadIdx.x;
    int w = tid >> 6, l = tid & 63;

    // stage A tile (32 rows x 400 B contiguous)
    {
        const uint4* src = (const uint4*)(fsp + ((size_t)b * N_ + r0) * PSTR);
        uint4* dst = (uint4*)Al;
        for (int i = tid; i < 800; i += 256) dst[i] = src[i];
    }
    __syncthreads();
    int rt = w & 1, cg = w >> 1;
    bf16x8 Af[6];
    {
        int row = rt * 16 + (l & 15);
        int koff = (l >> 4) * 8;
#pragma unroll
        for (int s = 0; s < 6; ++s)
            Af[s] = *(const bf16x8*)&Al[row * PSTR + s * 32 + koff];
    }
    __syncthreads();          // Al dead; pool/cnt region free
    if (tid < 32) cnt[tid] = 0u;

    int srow = w * 8 + (l >> 3);    // selection/filter row of this lane
    int sq_  = l & 7;               // col sub-lane
    const int Asel[9] = {0, 1, 2, 0, 1, 2, 3, 4, 5};
    const int Bsel[9] = {0, 1, 2, 3, 4, 5, 0, 1, 2};

    for (int pass = 0; pass < 2; ++pass) {
        for (int ch = 0; ch < 49; ++ch) {
            int c0 = ch * 64;
            __syncthreads();     // prior Bl/distl reads finished
            {
                const uint4* src = (const uint4*)(fsp + ((size_t)b * N_ + c0) * PSTR);
                uint4* dst = (uint4*)Bl;
                for (int i = tid; i < 1600; i += 256) dst[i] = src[i];
            }
            if (tid < 64) sqtl[tid] = sq32[b * N_ + c0 + tid];
            __syncthreads();
#pragma unroll
            for (int ct = 0; ct < 2; ++ct) {
                int colr = cg * 32 + ct * 16 + (l & 15);
                int koff = (l >> 4) * 8;
                bf16x8 Bf[6];
#pragma unroll
                for (int s = 0; s < 6; ++s)
                    Bf[s] = *(const bf16x8*)&Bl[colr * PSTR + s * 32 + koff];
                f32x4 acc = {0.f, 0.f, 0.f, 0.f};
#pragma unroll
                for (int s = 0; s < 9; ++s)
                    acc = __builtin_amdgcn_mfma_f32_16x16x32_bf16(Af[Asel[s]], Bf[Bsel[s]], acc, 0, 0, 0);
                float sv = sqtl[colr];
                int rowb = rt * 16 + (l >> 4) * 4;   // C/D: col=lane&15, row=(lane>>4)*4+reg
                unsigned gcol = (unsigned)(c0 + colr);
#pragma unroll
                for (int j = 0; j < 4; ++j) {
                    float d = sv - 2.f * acc[j];     // per-row-constant sqn dropped (order-invariant)
                    unsigned u = __float_as_uint(d);
                    unsigned ku = (u & 0x80000000u) ? ~u : (u | 0x80000000u);  // monotone flip
                    distl[(rowb + j) * DSTR + colr] = (ku & 0xFFFFF000u) | gcol;
                }
            }
            __syncthreads();
            if (pass == 0) {
                unsigned m = 0xFFFFFFFFu;
#pragma unroll
                for (int i = 0; i < 8; ++i) {
                    unsigned v = distl[srow * DSTR + sq_ + 8 * i];
                    m = (v < m) ? v : m;
                }
#pragma unroll
                for (int off = 1; off <= 4; off <<= 1) {
                    unsigned o = (unsigned)__shfl_xor((int)m, off, 64);
                    m = (o < m) ? o : m;
                }
                if (sq_ == 0) cmin[srow * 50 + ch] = (unsigned short)(m >> 16);
            } else {
                unsigned t = (unsigned)t16l[srow];
                if ((unsigned)cmin[srow * 50 + ch] <= t) {
#pragma unroll
                    for (int i = 0; i < 8; ++i) {
                        unsigned key = distl[srow * DSTR + sq_ + 8 * i];
                        if ((key >> 16) <= t) {
                            unsigned pos = atomicAdd(&cnt[srow], 1u);
                            if (pos < (unsigned)CAP_) pool[srow * CAP_ + pos] = key;
                        }
                    }
                }
            }
        }
        if (pass == 0) {
            __syncthreads();
            if (tid < 32) {
                int kd[16];
#pragma unroll
                for (int j = 0; j < 16; ++j) kd[j] = 0x7fffffff;
                for (int ch = 0; ch < 49; ++ch) {
                    int v = (int)cmin[tid * 50 + ch];
                    if (v < kd[15]) {
                        kd[15] = v;
#pragma unroll
                        for (int j = 15; j >= 1; --j) {
                            if (kd[j] < kd[j - 1]) { int tt = kd[j]; kd[j] = kd[j - 1]; kd[j - 1] = tt; }
                        }
                    }
                }
                t16l[tid] = (unsigned short)kd[15];
            }
            __syncthreads();
        }
    }
    __syncthreads();
    if (tid < 32) poolCnt[(size_t)b * N_ + r0 + tid] = cnt[tid];
    for (int i = tid; i < 32 * CAP_; i += 256) {
        int row = i / CAP_, k = i % CAP_;
        poolK[((size_t)b * N_ + r0 + row) * CAP_ + k] = pool[row * CAP_ + k];
    }
}

// ---------------- fp64 exact re-rank of variable pool -> top-9 set ----------------
// one wave per row; one lane per pool candidate; 9 lexicographic wave-min extractions
__global__ __launch_bounds__(256) void k_rerank_d(const unsigned* __restrict__ poolK,
                                                  const unsigned* __restrict__ poolCnt,
                                                  const double* __restrict__ ftp64,
                                                  const double* __restrict__ sq64,
                                                  int* __restrict__ idx) {
    int tid = threadIdx.x;
    int wv = tid >> 6, l = tid & 63;
    int rr = blockIdx.x * 4 + wv;
    int b = rr / N_;
    unsigned cnt = poolCnt[rr];
    if (cnt > (unsigned)CAP_) cnt = CAP_;
    double d = 1e300;
    int j = 0x7fffffff;
    if (l < (int)cnt) {
        unsigned key = poolK[(size_t)rr * CAP_ + l];
        j = (int)(key & 0xFFFu);
        const double* qb = ftp64 + (size_t)rr * C_;
        const double* cb = ftp64 + ((size_t)b * N_ + j) * C_;
        double s0 = 0.0, s1 = 0.0;
#pragma unroll
        for (int k = 0; k < 96; k += 2) {
            s0 += qb[k] * cb[k];
            s1 += qb[k + 1] * cb[k + 1];
        }
        d = sq64[(size_t)b * N_ + j] - 2.0 * (s0 + s1);   // per-row sqn dropped
    }
#pragma unroll
    for (int r = 0; r < 9; ++r) {
        double dm = d;
        int jm = j;
#pragma unroll
        for (int off = 1; off <= 32; off <<= 1) {
            double od = __shfl_xor(dm, off, 64);
            int oj = __shfl_xor(jm, off, 64);
            if (od < dm || (od == dm && oj < jm)) { dm = od; jm = oj; }
        }
        if (l == 0) idx[(size_t)rr * 9 + r] = jm;
        if (j == jm) d = 1e300;    // retire winner (j unique per lane)
    }
}

// ---------------- u = ft·(Wtop-Wbot) + b_edge (mode 0), v = ft·Wbot (mode 1) ----------------
__global__ __launch_bounds__(512) void k_gemm_uv(const float* __restrict__ ftc,
                                                 const float* __restrict__ We,
                                                 const float* __restrict__ beb,
                                                 float* __restrict__ out, int mode) {
    __shared__ float Wl[96 * 48];
    int tid = threadIdx.x;
    int rl = tid & 255, h = tid >> 8;
    int dbase = blockIdx.y * 48;
    for (int q = tid; q < 96 * 48; q += 512) {
        int c = q / 48, dd = q % 48;
        float w = We[(96 + c) * C2_ + dbase + dd];
        if (mode == 0) w = We[c * C2_ + dbase + dd] - w;
        Wl[c * 48 + dd] = w;
    }
    __syncthreads();
    int r = blockIdx.x * 256 + rl;
    int b = r / N_, n = r - b * N_;
    float acc[24];
#pragma unroll
    for (int i = 0; i < 24; i++) acc[i] = 0.f;
    const float* xp = ftc + (size_t)b * C_ * N_ + n;
    for (int c = 0; c < 96; ++c) {
        float xv = xp[(size_t)c * N_];
        const float4* w4 = (const float4*)&Wl[c * 48 + h * 24];
#pragma unroll
        for (int i = 0; i < 6; ++i) {
            float4 w = w4[i];
            acc[i * 4 + 0] += xv * w.x;
            acc[i * 4 + 1] += xv * w.y;
            acc[i * 4 + 2] += xv * w.z;
            acc[i * 4 + 3] += xv * w.w;
        }
    }
    int d0 = dbase + h * 24;
    float* op = out + (size_t)r * C2_ + d0;
#pragma unroll
    for (int i = 0; i < 6; ++i) {
        float4 o;
        o.x = acc[i * 4 + 0]; o.y = acc[i * 4 + 1];
        o.z = acc[i * 4 + 2]; o.w = acc[i * 4 + 3];
        if (mode == 0) {
            o.x += beb[d0 + i * 4 + 0];
            o.y += beb[d0 + i * 4 + 1];
            o.z += beb[d0 + i * 4 + 2];
            o.w += beb[d0 + i * 4 + 3];
        }
        ((float4*)op)[i] = o;
    }
}

// ---------------- edge-BN stats: e = u[n,d] + v[j,d] over all (row,k) ----------------
__global__ __launch_bounds__(192) void k_bne_stats(const float* __restrict__ u,
                                                   const float* __restrict__ v,
                                                   const int* __restrict__ idx,
                                                   float* __restrict__ partial) {
    int d = threadIdx.x;
    int row0 = blockIdx.x * 32;
    int b = row0 / N_;
    float s = 0.f, ss = 0.f;
    for (int r = 0; r < 32; ++r) {
        int row = row0 + r;
        float ud = u[(size_t)row * C2_ + d];
        const int* ip = idx + (size_t)row * 9;
#pragma unroll
        for (int k = 0; k < 9; k++) {
            int j = ip[k];
            float e = ud + v[((size_t)b * N_ + j) * C2_ + d];
            s += e;
            ss += e * e;
        }
    }
    partial[(size_t)blockIdx.x * 384 + d] = s;
    partial[(size_t)blockIdx.x * 384 + 192 + d] = ss;
}

// ---------------- edge BN+relu+max over k, then fc2 (192->96) ----------------
__global__ __launch_bounds__(192) void k_edge_fc2(const float* __restrict__ u,
                                                  const float* __restrict__ v,
                                                  const int* __restrict__ idx,
                                                  const float* __restrict__ statsE,
                                                  const float* __restrict__ ge,
                                                  const float* __restrict__ bee,
                                                  const float* __restrict__ W2,
                                                  const float* __restrict__ b2,
                                                  float* __restrict__ out2) {
    __shared__ float gl[16][C2_];
    __shared__ float g2[C_][16];
    int tid = threadIdx.x;
    int row0 = blockIdx.x * 16;
    int b = row0 / N_;
    int n0 = row0 - b * N_;
    {
        int d = tid;
        float m = statsE[d * 2], rs = statsE[d * 2 + 1];
        float ga = ge[d], bb = bee[d];
        for (int r = 0; r < 16; ++r) {
            int row = row0 + r;
            float ud = u[(size_t)row * C2_ + d];
            const int* ip = idx + (size_t)row * 9;
            float gm = 0.f;                      // relu-then-max == max with 0
#pragma unroll
            for (int k = 0; k < 9; k++) {
                int j = ip[k];
                float e = ud + v[((size_t)b * N_ + j) * C2_ + d];
                float val = ga * (e - m) * rs + bb;
                gm = fmaxf(gm, val);
            }
            gl[r][d] = gm;
        }
    }
    __syncthreads();
    {
        int rr = tid / 24;
        int dq = tid % 24;
        for (int rep = 0; rep < 2; ++rep) {
            int r = rr + rep * 8;
            float4 acc = *(const float4*)&b2[dq * 4];
            for (int d = 0; d < C2_; ++d) {
                float gv = gl[r][d];
                float4 w = *(const float4*)&W2[d * C_ + dq * 4];
                acc.x += gv * w.x;
                acc.y += gv * w.y;
                acc.z += gv * w.z;
                acc.w += gv * w.w;
            }
            g2[dq * 4 + 0][r] = acc.x;
            g2[dq * 4 + 1][r] = acc.y;
            g2[dq * 4 + 2][r] = acc.z;
            g2[dq * 4 + 3][r] = acc.w;
        }
    }
    __syncthreads();
    for (int q = tid; q < 96 * 4; q += 192) {
        int dd = q / 4, part = q % 4;
        float4 val = *(const float4*)&g2[dd][part * 4];
        *(float4*)&out2[((size_t)b * C_ + dd) * N_ + n0 + part * 4] = val;
    }
}

// ---------------- t = bn2(out2) + x ----------------
__global__ __launch_bounds__(256) void k_bn2_add(const float* __restrict__ out2,
                                                 const float* __restrict__ x,
                                                 const float* __restrict__ stats,
                                                 const float* __restrict__ g,
                                                 const float* __restrict__ be,
                                                 float* __restrict__ t) {
    int i = blockIdx.x * 256 + threadIdx.x;
    if (i >= B_ * C_ * N_) return;
    int c = (i / N_) % C_;
    t[i] = g[c] * (out2[i] - stats[c * 2]) * stats[c * 2 + 1] + be[c] + x[i];
}

// ---------------- s = relu(sabn(t)) ----------------
__global__ __launch_bounds__(256) void k_sabn_relu(const float* __restrict__ t,
                                                   const float* __restrict__ stats,
                                                   const float* __restrict__ g,
                                                   const float* __restrict__ be,
                                                   float* __restrict__ s) {
    int i = blockIdx.x * 256 + threadIdx.x;
    if (i >= B_ * C_ * N_) return;
    int c = (i / N_) % C_;
    s[i] = fmaxf(g[c] * (t[i] - stats[c * 2]) * stats[c * 2 + 1] + be[c], 0.f);
}

// ---------------- conv 3x3 stride 2 pad 1, 96->192 ----------------
__global__ __launch_bounds__(256) void k_conv(const float* __restrict__ s,
                                              const float* __restrict__ Wd,
                                              const float* __restrict__ bd,
                                              float* __restrict__ z) {
    __shared__ float Wl[96 * 9 * 16];
    int b = blockIdx.z;
    int oc0 = blockIdx.y * 16;
    int p = blockIdx.x * 256 + threadIdx.x;
    for (int i = threadIdx.x; i < 96 * 9 * 16; i += 256) {
        int oc = i & 15;
        int icq = i >> 4;
        Wl[i] = Wd[(size_t)(oc0 + oc) * 864 + icq];
    }
    __syncthreads();
    if (p >= NO_) return;
    int oh = p / HO_, ow = p % HO_;
    float acc[16];
#pragma unroll
    for (int i = 0; i < 16; i++) acc[i] = 0.f;
    int ih0 = oh * 2 - 1, iw0 = ow * 2 - 1;
    const float* sb = s + (size_t)b * C_ * N_;
    for (int ic = 0; ic < 96; ++ic) {
        const float* sp = sb + (size_t)ic * N_;
        float in[9];
#pragma unroll
        for (int kh = 0; kh < 3; kh++) {
            int ih = ih0 + kh;
            bool okh = (unsigned)ih < 56u;
#pragma unroll
            for (int kw = 0; kw < 3; kw++) {
                int iw = iw0 + kw;
                bool ok = okh && ((unsigned)iw < 56u);
                in[kh * 3 + kw] = ok ? sp[ih * 56 + iw] : 0.f;
            }
        }
#pragma unroll
        for (int q = 0; q < 9; q++) {
            float iv = in[q];
            const float4* w4 = (const float4*)&Wl[(ic * 9 + q) * 16];
#pragma unroll
            for (int j = 0; j < 4; j++) {
                float4 w = w4[j];
                acc[j * 4 + 0] += iv * w.x;
                acc[j * 4 + 1] += iv * w.y;
                acc[j * 4 + 2] += iv * w.z;
                acc[j * 4 + 3] += iv * w.w;
            }
        }
    }
#pragma unroll
    for (int i = 0; i < 16; i++)
        z[((size_t)b * OUP_ + oc0 + i) * NO_ + p] = acc[i] + bd[oc0 + i];
}

// ---------------- out = relu(dwbn(z)) ----------------
__global__ __launch_bounds__(256) void k_out(const float* __restrict__ z,
                                             const float* __restrict__ stats,
                                             const float* __restrict__ g,
                                             const float* __restrict__ be,
                                             float* __restrict__ out) {
    int i = blockIdx.x * 256 + threadIdx.x;
    if (i >= B_ * OUP_ * NO_) return;
    int c = (i / NO_) % OUP_;
    out[i] = fmaxf(g[c] * (z[i] - stats[c * 2]) * stats[c * 2 + 1] + be[c], 0.f);
}

extern "C" void kernel_launch(void* const* d_in, const int* in_sizes, int n_in,
                              void* d_out, int out_size, void* d_ws, size_t ws_size,
                              hipStream_t stream) {
    const float* x     = (const float*)d_in[0];
    const float* W_fc1 = (const float*)d_in[1];
    const float* b_fc1 = (const float*)d_in[2];
    const float* g_bn1 = (const float*)d_in[3];
    const float* be_bn1= (const float*)d_in[4];
    const float* W_edge= (const float*)d_in[5];
    const float* b_edge= (const float*)d_in[6];
    const float* g_bne = (const float*)d_in[7];
    const float* be_bne= (const float*)d_in[8];
    const float* W_fc2 = (const float*)d_in[9];
    const float* b_fc2 = (const float*)d_in[10];
    const float* g_bn2 = (const float*)d_in[11];
    const float* be_bn2= (const float*)d_in[12];
    const float* g_sabn= (const float*)d_in[13];
    const float* be_sabn=(const float*)d_in[14];
    const float* W_dw  = (const float*)d_in[15];
    const float* b_dw  = (const float*)d_in[16];
    const float* g_dwbn= (const float*)d_in[17];
    const float* be_dwbn=(const float*)d_in[18];

    // byte-offset workspace layout with lifetime-based aliasing (~77 MB)
    char* base = (char*)d_ws;
    float*  ftc   = (float*)(base + 0);                    //  9,633,792  [bn1 -> gemm_uv]; then sbuf
    float*  ftp32 = (float*)(base + 9633792);              //  9,633,792  [bn1 -> split];   then tbuf
    double* ftp64 = (double*)(base + 19267584);            // 19,267,584  [bn1 -> rerank];  then uu
    double* sq64  = (double*)(base + 38535168);            //    200,704
    double* yd    = (double*)(base + 38735872);            // 19,267,584  [fc1 -> bn1]
    unsigned short* fsp = (unsigned short*)(base + 38735872); // 10,035,200 [split -> dist] (aliases yd)
    float*  out2  = (float*)(base + 38735872);             //  9,633,792  [edge_fc2 -> bn2] (aliases fsp)
    unsigned* poolK = (unsigned*)(base + 48771072);        //  6,422,528  [dist -> rerank]
    float*  zbuf  = (float*)(base + 48771072);             //  4,816,896  [conv -> out] (aliases poolK)
    int*    idx   = (int*)(base + 55193600);               //    903,168  [rerank -> edge]
    float*  uu    = (float*)(base + 19267584);             // 19,267,584  [gemm -> edge_fc2] (aliases ftp64, after rerank)
    float*  vv    = (float*)(base + 56096768);             // 19,267,584  [gemm -> edge_fc2]
    float*  tbuf  = (float*)(base + 9633792);              //  [bn2 -> sabn]  (aliases ftp32)
    float*  sbuf  = (float*)(base + 0);                    //  [sabn -> conv] (aliases ftc)
    float*  partial = (float*)(base + 75364352);           //  1,204,224 max [bne_stats etc.]
    double* partiald = (double*)(base + 75364352);         //     24,576 (earlier use, same region)
    double* stats1d = (double*)(base + 76568576);
    float*  statsE  = (float*)(base + 76570112);
    float*  stats2  = (float*)(base + 76571648);
    float*  statsS  = (float*)(base + 76573184);
    float*  statsD  = (float*)(base + 76574720);
    float*  sq32    = (float*)(base + 76576256);           //    100,352
    unsigned* poolCnt = (unsigned*)(base + 76676608);      //    100,352 -> ends 76,776,960

    // fc1 + BN1 (fp64 path, exact stats + features)
    k_fc1_d<<<dim3(98, 2), 512, 0, stream>>>(x, W_fc1, b_fc1, yd);
    k_stats_chan_d<<<dim3(96, 16), 256, 0, stream>>>(yd, partiald);
    k_stats_reduce_d<<<1, 256, 0, stream>>>(partiald, stats1d);
    k_bn1_apply_d<<<9408, 256, 0, stream>>>(yd, stats1d, g_bn1, be_bn1, ftc, ftp32, ftp64);
    k_sqrows_d<<<98, 256, 0, stream>>>(ftp64, sq64, sq32);

    // kNN: split-bf16 MFMA + threshold/compaction -> pool, fp64 re-rank -> exact top-9 set
    k_split<<<1176, 256, 0, stream>>>(ftp32, fsp);
    k_dist_mfma<<<dim3(98, B_), 256, 0, stream>>>(fsp, sq32, poolK, poolCnt);
    k_rerank_d<<<6272, 256, 0, stream>>>(poolK, poolCnt, ftp64, sq64, idx);

    // edge GEMM decomposition: u = ft·(Wtop-Wbot)+b_edge, v = ft·Wbot (uu overwrites ftp64 after rerank)
    k_gemm_uv<<<dim3(98, 4), 512, 0, stream>>>(ftc, W_edge, b_edge, uu, 0);
    k_gemm_uv<<<dim3(98, 4), 512, 0, stream>>>(ftc, W_edge, b_edge, vv, 1);

    // edge BN stats, then BN+relu+max+fc2
    k_bne_stats<<<784, 192, 0, stream>>>(uu, vv, idx, partial);
    k_stats_reduce_b2<<<192, 256, 0, stream>>>(partial, statsE, 1.0f / 225792.0f);
    k_edge_fc2<<<1568, 192, 0, stream>>>(uu, vv, idx, statsE, g_bne, be_bne, W_fc2, b_fc2, out2);

    // BN2 + shortcut
    k_stats_chan<<<dim3(96, 16), 256, 0, stream>>>(out2, partial, 96, N_, R_);
    k_stats_reduce<<<1, 256, 0, stream>>>(partial, stats2, 96, 16, 1.0f / (float)R_);
    k_bn2_add<<<9408, 256, 0, stream>>>(out2, x, stats2, g_bn2, be_bn2, tbuf);

    // sabn + relu
    k_stats_chan<<<dim3(96, 16), 256, 0, stream>>>(tbuf, partial, 96, N_, R_);
    k_stats_reduce<<<1, 256, 0, stream>>>(partial, statsS, 96, 16, 1.0f / (float)R_);
    k_sabn_relu<<<9408, 256, 0, stream>>>(tbuf, statsS, g_sabn, be_sabn, sbuf);

    // conv + dwbn + relu
    k_conv<<<dim3(4, 12, 8), 256, 0, stream>>>(sbuf, W_dw, b_dw, zbuf);
    k_stats_chan<<<dim3(192, 8), 256, 0, stream>>>(zbuf, partial, 192, NO_, 6272);
    k_stats_reduce<<<1, 256, 0, stream>>>(partial, statsD, 192, 8, 1.0f / 6272.0f);
    k_out<<<4705, 256, 0, stream>>>(zbuf, statsD, g_dwbn, be_dwbn, (float*)d_out);
}

// Round 6
// 889.708 us; speedup vs baseline: 1.1754x; 1.1754x over previous
//
#include <hip/hip_runtime.h>
#include <math.h>

#define B_   8
#define C_   96
#define C2_  192
#define N_   3136        // 56*56
#define R_   25088       // B_*N_
#define OUP_ 192
#define HO_  28
#define NO_  784         // 28*28
#define EPS_ 1e-5f
#define PSTR 200         // padded split-bf16 point stride (elements)
#define QCH  196         // quarter-chunks (16 cols each) per row
#define CAP2 40          // per-row candidate pool cap

typedef short bf16x8 __attribute__((ext_vector_type(8)));
typedef float f32x4  __attribute__((ext_vector_type(4)));

// DPP min over a 16-lane row segment (accumulates toward lane 15)
template<int CTRL>
__device__ __forceinline__ float dppmin(float x) {
    int xi = __float_as_int(x);
    int yi = __builtin_amdgcn_update_dpp(xi, xi, CTRL, 0xf, 0xf, false);
    return fminf(x, __int_as_float(yi));
}

// ---------------- fc1 (fp64 accumulate): yd[b,d,n] = sum_c x[b,c,n]*W1[c,d] + b1[d] ----------------
__global__ __launch_bounds__(512) void k_fc1_d(const float* __restrict__ x,
                                               const float* __restrict__ W1,
                                               const float* __restrict__ b1,
                                               double* __restrict__ yd) {
    __shared__ double Wl[96 * 48];
    int tid = threadIdx.x;
    int rl = tid & 255, h = tid >> 8;
    int dbase = blockIdx.y * 48;
    for (int q = tid; q < 96 * 48; q += 512) {
        int c = q / 48, dd = q % 48;
        Wl[c * 48 + dd] = (double)W1[c * 96 + dbase + dd];
    }
    __syncthreads();
    int r = blockIdx.x * 256 + rl;
    int b = r / N_;
    int n = r - b * N_;
    double acc[24];
#pragma unroll
    for (int i = 0; i < 24; i++) acc[i] = 0.0;
    const float* xp = x + (size_t)b * C_ * N_ + n;
    for (int c = 0; c < 96; ++c) {
        double xv = (double)xp[(size_t)c * N_];
        const double* w = &Wl[c * 48 + h * 24];
#pragma unroll
        for (int i = 0; i < 24; ++i) acc[i] += xv * w[i];
    }
    int d0 = dbase + h * 24;
#pragma unroll
    for (int i = 0; i < 24; i++) {
        int d = d0 + i;
        yd[((size_t)b * C_ + d) * N_ + n] = acc[i] + (double)b1[d];
    }
}

// ---------------- fp64 per-channel stats over yd ----------------
__global__ __launch_bounds__(256) void k_stats_chan_d(const double* __restrict__ src,
                                                      double* __restrict__ partial) {
    int c = blockIdx.x;
    int chunk = blockIdx.y;
    const int SPLIT = 16;
    double s = 0.0, ss = 0.0;
    for (int j = chunk * 256 + threadIdx.x; j < R_; j += SPLIT * 256) {
        int b = j / N_, n = j - b * N_;
        double v = src[((size_t)b * C_ + c) * N_ + n];
        s += v;
        ss += v * v;
    }
    __shared__ double red[8];
    for (int off = 32; off; off >>= 1) {
        s += __shfl_down(s, off, 64);
        ss += __shfl_down(ss, off, 64);
    }
    int lane = threadIdx.x & 63, w = threadIdx.x >> 6;
    if (lane == 0) { red[w * 2] = s; red[w * 2 + 1] = ss; }
    __syncthreads();
    if (threadIdx.x == 0) {
        s = red[0] + red[2] + red[4] + red[6];
        ss = red[1] + red[3] + red[5] + red[7];
        partial[(c * SPLIT + chunk) * 2] = s;
        partial[(c * SPLIT + chunk) * 2 + 1] = ss;
    }
}

__global__ void k_stats_reduce_d(const double* __restrict__ partial, double* __restrict__ stats) {
    int c = blockIdx.x * blockDim.x + threadIdx.x;
    if (c >= 96) return;
    double s = 0.0, ss = 0.0;
    for (int k = 0; k < 16; k++) {
        s += partial[(c * 16 + k) * 2];
        ss += partial[(c * 16 + k) * 2 + 1];
    }
    double m = s / (double)R_;
    double var = ss / (double)R_ - m * m;
    stats[c * 2] = m;
    stats[c * 2 + 1] = 1.0 / sqrt(var + 1e-5);
}

// ---------------- fp32 per-channel stats ----------------
__global__ __launch_bounds__(256) void k_stats_chan(const float* __restrict__ src,
                                                    float* __restrict__ partial,
                                                    int Cn, int Nsp, int total) {
    int c = blockIdx.x;
    int chunk = blockIdx.y;
    int SPLIT = gridDim.y;
    float s = 0.f, ss = 0.f;
    for (int j = chunk * 256 + threadIdx.x; j < total; j += SPLIT * 256) {
        int b = j / Nsp, n = j - b * Nsp;
        float v = src[((size_t)b * Cn + c) * Nsp + n];
        s += v;
        ss += v * v;
    }
    __shared__ float red[8];
    for (int off = 32; off; off >>= 1) {
        s += __shfl_down(s, off, 64);
        ss += __shfl_down(ss, off, 64);
    }
    int lane = threadIdx.x & 63, w = threadIdx.x >> 6;
    if (lane == 0) { red[w * 2] = s; red[w * 2 + 1] = ss; }
    __syncthreads();
    if (threadIdx.x == 0) {
        s = red[0] + red[2] + red[4] + red[6];
        ss = red[1] + red[3] + red[5] + red[7];
        partial[(c * SPLIT + chunk) * 2] = s;
        partial[(c * SPLIT + chunk) * 2 + 1] = ss;
    }
}

__global__ void k_stats_reduce(const float* __restrict__ partial, float* __restrict__ stats,
                               int Cn, int SPLIT, float invcount) {
    int c = blockIdx.x * blockDim.x + threadIdx.x;
    if (c >= Cn) return;
    float s = 0.f, ss = 0.f;
    for (int k = 0; k < SPLIT; k++) {
        s += partial[(c * SPLIT + k) * 2];
        ss += partial[(c * SPLIT + k) * 2 + 1];
    }
    float m = s * invcount;
    float var = ss * invcount - m * m;
    stats[c * 2] = m;
    stats[c * 2 + 1] = 1.0f / sqrtf(var + EPS_);
}

// parallel reduce for k_bne_stats partials: one block per channel
__global__ __launch_bounds__(256) void k_stats_reduce_b2(const float* __restrict__ partial,
                                                         float* __restrict__ stats,
                                                         float invcount) {
    int c = blockIdx.x;      // 0..191
    float s = 0.f, ss = 0.f;
    for (int k = threadIdx.x; k < 784; k += 256) {
        s  += partial[(size_t)k * 384 + c];
        ss += partial[(size_t)k * 384 + 192 + c];
    }
    __shared__ float red[8];
    for (int off = 32; off; off >>= 1) {
        s += __shfl_down(s, off, 64);
        ss += __shfl_down(ss, off, 64);
    }
    int lane = threadIdx.x & 63, w = threadIdx.x >> 6;
    if (lane == 0) { red[w * 2] = s; red[w * 2 + 1] = ss; }
    __syncthreads();
    if (threadIdx.x == 0) {
        s = red[0] + red[2] + red[4] + red[6];
        ss = red[1] + red[3] + red[5] + red[7];
        float m = s * invcount;
        float var = ss * invcount - m * m;
        stats[c * 2] = m;
        stats[c * 2 + 1] = 1.0f / sqrtf(var + EPS_);
    }
}

// ---------------- apply BN1 (fp64); emit ftc (f32 ch-major), ftp32/ftp64 (point-major) ----------------
__global__ __launch_bounds__(256) void k_bn1_apply_d(const double* __restrict__ yd,
                                                     const double* __restrict__ stats,
                                                     const float* __restrict__ g,
                                                     const float* __restrict__ be,
                                                     float* __restrict__ ftc,
                                                     float* __restrict__ ftp32,
                                                     double* __restrict__ ftp64) {
    int i = blockIdx.x * 256 + threadIdx.x;
    if (i >= B_ * C_ * N_) return;
    int n = i % N_;
    int bc = i / N_;
    int c = bc % C_;
    int b = bc / C_;
    double m = stats[c * 2], rs = stats[c * 2 + 1];
    double v = (double)g[c] * (yd[i] - m) * rs + (double)be[c];
    float vf = (float)v;
    ftc[i] = vf;
    size_t pp = ((size_t)b * N_ + n) * C_ + c;
    ftp32[pp] = vf;
    ftp64[pp] = v;
}

// ---------------- row squared norms: fp64 exact + fp32 copy ----------------
__global__ __launch_bounds__(256) void k_sqrows_d(const double* __restrict__ ftp64,
                                                  double* __restrict__ sq64,
                                                  float* __restrict__ sq32) {
    int r = blockIdx.x * 256 + threadIdx.x;
    if (r >= R_) return;
    const double* p = ftp64 + (size_t)r * C_;
    double s = 0.0;
    for (int q = 0; q < 96; q++) s += p[q] * p[q];
    sq64[r] = s;
    sq32[r] = (float)s;
}

// ---------------- split ft into bf16 hi/lo pairs (point-major, padded stride) ----------------
__global__ __launch_bounds__(256) void k_split(const float* __restrict__ ftp32,
                                               unsigned short* __restrict__ fsp) {
    int t = blockIdx.x * 256 + threadIdx.x;
    if (t >= R_ * 12) return;
    int p = t / 12, g = t % 12;
    const float* src = ftp32 + (size_t)p * C_ + g * 8;
    unsigned short hi[8], lo[8];
#pragma unroll
    for (int j = 0; j < 8; ++j) {
        float x = src[j];
        unsigned u = __float_as_uint(x);
        unsigned r = (u + 0x7fffu + ((u >> 16) & 1u)) >> 16;       // RNE to bf16
        float hf = __uint_as_float(r << 16);
        hi[j] = (unsigned short)r;
        float res = x - hf;                                        // exact
        unsigned u2 = __float_as_uint(res);
        unsigned r2 = (u2 + 0x7fffu + ((u2 >> 16) & 1u)) >> 16;
        lo[j] = (unsigned short)r2;
    }
    unsigned short* dh = fsp + (size_t)p * PSTR + g * 8;
    unsigned short* dl = dh + 96;
    *(ushort4*)dh       = *(ushort4*)&hi[0];
    *(ushort4*)(dh + 4) = *(ushort4*)&hi[4];
    *(ushort4*)dl       = *(ushort4*)&lo[0];
    *(ushort4*)(dl + 4) = *(ushort4*)&lo[4];
}

// ---------------- split-bf16 MFMA distance, two-pass threshold + compaction (reg-resident) ----------------
// block: 64 query rows x all 3136 candidates (49 chunks of 64). 4 waves; wave w owns
// ALL 64 rows x 16 cols (quarter-chunk q = ch*4+w). A frags persistent (24 bf16x8/lane).
// pass 0: per-row quarter-chunk minima via DPP row_shr min tree -> cmin (u16 monotone keys)
// mid:    t16 = 16th smallest of 196 minima per row -> float threshold
// pass 1: recompute d; compact cols with d <= t16f into per-row pool (>=16 guaranteed)
__global__ __launch_bounds__(256) void k_dist2(const unsigned short* __restrict__ fsp,
                                               const float* __restrict__ sq32,
                                               unsigned short* __restrict__ poolC,
                                               unsigned* __restrict__ poolCnt) {
    __shared__ __align__(16) char lds[56576];
    unsigned short* Bl    = (unsigned short*)lds;            // [0,25600)   64x200 u16
    unsigned short* cminL = (unsigned short*)(lds + 25600);  // [25600,50688) 196x64 u16
    unsigned short* Al    = (unsigned short*)(lds + 25600);  // staging alias (dead before cmin)
    unsigned short* poolL = (unsigned short*)(lds + 50688);  // [50688,55808) 64xCAP2 u16
    unsigned*       cntL  = (unsigned*)(lds + 55808);        // 64 u32
    float*          t16fL = (float*)(lds + 56064);           // 64 f32
    float*          sqtl  = (float*)(lds + 56320);           // 64 f32

    int b = blockIdx.y;
    int r0 = blockIdx.x * 64;
    int tid = threadIdx.x;
    int w = tid >> 6, l = tid & 63;

    // stage A tile (64 rows x 400B contiguous) into alias region
    {
        const uint4* src = (const uint4*)(fsp + ((size_t)b * N_ + r0) * PSTR);
        uint4* dst = (uint4*)Al;
        for (int i = tid; i < 1600; i += 256) dst[i] = src[i];
    }
    __syncthreads();
    const int koff = (l >> 4) * 8;
    bf16x8 Af[4][6];
#pragma unroll
    for (int rt = 0; rt < 4; ++rt)
#pragma unroll
        for (int s = 0; s < 6; ++s)
            Af[rt][s] = *(const bf16x8*)&Al[(rt * 16 + (l & 15)) * PSTR + s * 32 + koff];
    __syncthreads();   // Al dead; cmin region free

    const int cg = w;                       // wave's 16-col group within each 64-chunk
    const int colr = cg * 16 + (l & 15);
    const int Asel[9] = {0, 1, 2, 0, 1, 2, 3, 4, 5};
    const int Bsel[9] = {0, 1, 2, 3, 4, 5, 0, 1, 2};
    float t16r[16];

    for (int pass = 0; pass < 2; ++pass) {
        for (int ch = 0; ch < 49; ++ch) {
            int c0 = ch * 64;
            __syncthreads();     // prior Bl reads complete
            {
                const uint4* src = (const uint4*)(fsp + ((size_t)b * N_ + c0) * PSTR);
                uint4* dst = (uint4*)Bl;
                for (int i = tid; i < 1600; i += 256) dst[i] = src[i];
            }
            if (tid < 64) sqtl[tid] = sq32[b * N_ + c0 + tid];
            __syncthreads();
            bf16x8 Bf[6];
#pragma unroll
            for (int s = 0; s < 6; ++s)
                Bf[s] = *(const bf16x8*)&Bl[colr * PSTR + s * 32 + koff];
            f32x4 acc[4];
#pragma unroll
            for (int rt = 0; rt < 4; ++rt) acc[rt] = (f32x4){0.f, 0.f, 0.f, 0.f};
#pragma unroll
            for (int s = 0; s < 9; ++s)
#pragma unroll
                for (int rt = 0; rt < 4; ++rt)
                    acc[rt] = __builtin_amdgcn_mfma_f32_16x16x32_bf16(Af[rt][Asel[s]], Bf[Bsel[s]], acc[rt], 0, 0, 0);
            float sv = sqtl[colr];
            if (pass == 0) {
                // per-row min over this wave's 16 cols, fully in-register (DPP)
#pragma unroll
                for (int rt = 0; rt < 4; ++rt) {
#pragma unroll
                    for (int j = 0; j < 4; ++j) {
                        float d = fmaf(-2.f, acc[rt][j], sv);  // query norm dropped (order-invariant)
                        d = dppmin<0x111>(d);   // row_shr:1
                        d = dppmin<0x112>(d);   // row_shr:2
                        d = dppmin<0x114>(d);   // row_shr:4
                        d = dppmin<0x118>(d);   // row_shr:8 -> lane 15 of each 16-row has min
                        if ((l & 15) == 15) {
                            unsigned u = __float_as_uint(d);
                            unsigned ku = u ^ (0x80000000u | (unsigned)((int)u >> 31));  // monotone
                            cminL[(ch * 4 + cg) * 64 + rt * 16 + (l >> 4) * 4 + j] = (unsigned short)(ku >> 16);
                        }
                    }
                }
            } else {
#pragma unroll
                for (int rt = 0; rt < 4; ++rt) {
#pragma unroll
                    for (int j = 0; j < 4; ++j) {
                        float d = fmaf(-2.f, acc[rt][j], sv);
                        if (d <= t16r[rt * 4 + j]) {           // rare
                            int row = rt * 16 + (l >> 4) * 4 + j;
                            unsigned pos = atomicAdd(&cntL[row], 1u);
                            if (pos < (unsigned)CAP2) poolL[row * CAP2 + pos] = (unsigned short)(c0 + colr);
                        }
                    }
                }
            }
        }
        if (pass == 0) {
            __syncthreads();
            if (tid < 64) {
                unsigned short top[16];
#pragma unroll
                for (int j = 0; j < 16; ++j) top[j] = 0xFFFFu;
                for (int q = 0; q < QCH; ++q) {
                    unsigned short v = cminL[q * 64 + tid];
                    if (v < top[15]) {
                        top[15] = v;
#pragma unroll
                        for (int j = 15; j >= 1; --j)
                            if (top[j] < top[j - 1]) { unsigned short t = top[j]; top[j] = top[j - 1]; top[j - 1] = t; }
                    }
                }
                unsigned ku = ((unsigned)top[15] << 16) | 0xFFFFu;   // largest key with top16 == t16
                t16fL[tid] = (ku & 0x80000000u) ? __uint_as_float(ku ^ 0x80000000u)
                                                : __uint_as_float(~ku);
                cntL[tid] = 0u;
            }
            __syncthreads();
#pragma unroll
            for (int rt = 0; rt < 4; ++rt)
#pragma unroll
                for (int j = 0; j < 4; ++j)
                    t16r[rt * 4 + j] = t16fL[rt * 16 + (l >> 4) * 4 + j];
        }
    }
    __syncthreads();
    if (tid < 64) poolCnt[(size_t)b * N_ + r0 + tid] = cntL[tid];
    {
        unsigned* dst = (unsigned*)(poolC + ((size_t)b * N_ + r0) * CAP2);
        const unsigned* src = (const unsigned*)poolL;
        for (int i = tid; i < 64 * CAP2 / 2; i += 256) dst[i] = src[i];
    }
}

// ---------------- fp64 exact re-rank of variable pool -> top-9 set ----------------
// one wave per row; one lane per pool candidate; 9 lexicographic wave-min extractions
__global__ __launch_bounds__(256) void k_rerank_d(const unsigned short* __restrict__ poolC,
                                                  const unsigned* __restrict__ poolCnt,
                                                  const double* __restrict__ ftp64,
                                                  const double* __restrict__ sq64,
                                                  int* __restrict__ idx) {
    int tid = threadIdx.x;
    int wv = tid >> 6, l = tid & 63;
    int rr = blockIdx.x * 4 + wv;
    int b = rr / N_;
    unsigned cnt = poolCnt[rr];
    if (cnt > (unsigned)CAP2) cnt = CAP2;
    double d = 1e300;
    int j = 0x7fffffff;
    if (l < (int)cnt) {
        j = (int)poolC[(size_t)rr * CAP2 + l];
        const double* qb = ftp64 + (size_t)rr * C_;
        const double* cb = ftp64 + ((size_t)b * N_ + j) * C_;
        double s0 = 0.0, s1 = 0.0;
#pragma unroll
        for (int k = 0; k < 96; k += 2) {
            s0 += qb[k] * cb[k];
            s1 += qb[k + 1] * cb[k + 1];
        }
        d = sq64[(size_t)b * N_ + j] - 2.0 * (s0 + s1);   // per-row sqn dropped
    }
#pragma unroll
    for (int r = 0; r < 9; ++r) {
        double dm = d;
        int jm = j;
#pragma unroll
        for (int off = 1; off <= 32; off <<= 1) {
            double od = __shfl_xor(dm, off, 64);
            int oj = __shfl_xor(jm, off, 64);
            if (od < dm || (od == dm && oj < jm)) { dm = od; jm = oj; }
        }
        if (l == 0) idx[(size_t)rr * 9 + r] = jm;
        if (j == jm) d = 1e300;    // retire winner (j unique per lane)
    }
}

// ---------------- u = ft·(Wtop-Wbot) + b_edge (mode 0), v = ft·Wbot (mode 1) ----------------
__global__ __launch_bounds__(512) void k_gemm_uv(const float* __restrict__ ftc,
                                                 const float* __restrict__ We,
                                                 const float* __restrict__ beb,
                                                 float* __restrict__ out, int mode) {
    __shared__ float Wl[96 * 48];
    int tid = threadIdx.x;
    int rl = tid & 255, h = tid >> 8;
    int dbase = blockIdx.y * 48;
    for (int q = tid; q < 96 * 48; q += 512) {
        int c = q / 48, dd = q % 48;
        float w = We[(96 + c) * C2_ + dbase + dd];
        if (mode == 0) w = We[c * C2_ + dbase + dd] - w;
        Wl[c * 48 + dd] = w;
    }
    __syncthreads();
    int r = blockIdx.x * 256 + rl;
    int b = r / N_, n = r - b * N_;
    float acc[24];
#pragma unroll
    for (int i = 0; i < 24; i++) acc[i] = 0.f;
    const float* xp = ftc + (size_t)b * C_ * N_ + n;
    for (int c = 0; c < 96; ++c) {
        float xv = xp[(size_t)c * N_];
        const float4* w4 = (const float4*)&Wl[c * 48 + h * 24];
#pragma unroll
        for (int i = 0; i < 6; ++i) {
            float4 w = w4[i];
            acc[i * 4 + 0] += xv * w.x;
            acc[i * 4 + 1] += xv * w.y;
            acc[i * 4 + 2] += xv * w.z;
            acc[i * 4 + 3] += xv * w.w;
        }
    }
    int d0 = dbase + h * 24;
    float* op = out + (size_t)r * C2_ + d0;
#pragma unroll
    for (int i = 0; i < 6; ++i) {
        float4 o;
        o.x = acc[i * 4 + 0]; o.y = acc[i * 4 + 1];
        o.z = acc[i * 4 + 2]; o.w = acc[i * 4 + 3];
        if (mode == 0) {
            o.x += beb[d0 + i * 4 + 0];
            o.y += beb[d0 + i * 4 + 1];
            o.z += beb[d0 + i * 4 + 2];
            o.w += beb[d0 + i * 4 + 3];
        }
        ((float4*)op)[i] = o;
    }
}

// ---------------- edge-BN stats: e = u[n,d] + v[j,d] over all (row,k) ----------------
__global__ __launch_bounds__(192) void k_bne_stats(const float* __restrict__ u,
                                                   const float* __restrict__ v,
                                                   const int* __restrict__ idx,
                                                   float* __restrict__ partial) {
    int d = threadIdx.x;
    int row0 = blockIdx.x * 32;
    int b = row0 / N_;
    float s = 0.f, ss = 0.f;
    for (int r = 0; r < 32; ++r) {
        int row = row0 + r;
        float ud = u[(size_t)row * C2_ + d];
        const int* ip = idx + (size_t)row * 9;
#pragma unroll
        for (int k = 0; k < 9; k++) {
            int j = ip[k];
            float e = ud + v[((size_t)b * N_ + j) * C2_ + d];
            s += e;
            ss += e * e;
        }
    }
    partial[(size_t)blockIdx.x * 384 + d] = s;
    partial[(size_t)blockIdx.x * 384 + 192 + d] = ss;
}

// ---------------- edge BN+relu+max over k, then fc2 (192->96) ----------------
__global__ __launch_bounds__(192) void k_edge_fc2(const float* __restrict__ u,
                                                  const float* __restrict__ v,
                                                  const int* __restrict__ idx,
                                                  const float* __restrict__ statsE,
                                                  const float* __restrict__ ge,
                                                  const float* __restrict__ bee,
                                                  const float* __restrict__ W2,
                                                  const float* __restrict__ b2,
                                                  float* __restrict__ out2) {
    __shared__ float gl[16][C2_];
    __shared__ float g2[C_][16];
    int tid = threadIdx.x;
    int row0 = blockIdx.x * 16;
    int b = row0 / N_;
    int n0 = row0 - b * N_;
    {
        int d = tid;
        float m = statsE[d * 2], rs = statsE[d * 2 + 1];
        float ga = ge[d], bb = bee[d];
        for (int r = 0; r < 16; ++r) {
            int row = row0 + r;
            float ud = u[(size_t)row * C2_ + d];
            const int* ip = idx + (size_t)row * 9;
            float gm = 0.f;                      // relu-then-max == max with 0
#pragma unroll
            for (int k = 0; k < 9; k++) {
                int j = ip[k];
                float e = ud + v[((size_t)b * N_ + j) * C2_ + d];
                float val = ga * (e - m) * rs + bb;
                gm = fmaxf(gm, val);
            }
            gl[r][d] = gm;
        }
    }
    __syncthreads();
    {
        int rr = tid / 24;
        int dq = tid % 24;
        for (int rep = 0; rep < 2; ++rep) {
            int r = rr + rep * 8;
            float4 acc = *(const float4*)&b2[dq * 4];
            for (int d = 0; d < C2_; ++d) {
                float gv = gl[r][d];
                float4 w = *(const float4*)&W2[d * C_ + dq * 4];
                acc.x += gv * w.x;
                acc.y += gv * w.y;
                acc.z += gv * w.z;
                acc.w += gv * w.w;
            }
            g2[dq * 4 + 0][r] = acc.x;
            g2[dq * 4 + 1][r] = acc.y;
            g2[dq * 4 + 2][r] = acc.z;
            g2[dq * 4 + 3][r] = acc.w;
        }
    }
    __syncthreads();
    for (int q = tid; q < 96 * 4; q += 192) {
        int dd = q / 4, part = q % 4;
        float4 val = *(const float4*)&g2[dd][part * 4];
        *(float4*)&out2[((size_t)b * C_ + dd) * N_ + n0 + part * 4] = val;
    }
}

// ---------------- t = bn2(out2) + x ----------------
__global__ __launch_bounds__(256) void k_bn2_add(const float* __restrict__ out2,
                                                 const float* __restrict__ x,
                                                 const float* __restrict__ stats,
                                                 const float* __restrict__ g,
                                                 const float* __restrict__ be,
                                                 float* __restrict__ t) {
    int i = blockIdx.x * 256 + threadIdx.x;
    if (i >= B_ * C_ * N_) return;
    int c = (i / N_) % C_;
    t[i] = g[c] * (out2[i] - stats[c * 2]) * stats[c * 2 + 1] + be[c] + x[i];
}

// ---------------- s = relu(sabn(t)) ----------------
__global__ __launch_bounds__(256) void k_sabn_relu(const float* __restrict__ t,
                                                   const float* __restrict__ stats,
                                                   const float* __restrict__ g,
                                                   const float* __restrict__ be,
                                                   float* __restrict__ s) {
    int i = blockIdx.x * 256 + threadIdx.x;
    if (i >= B_ * C_ * N_) return;
    int c = (i / N_) % C_;
    s[i] = fmaxf(g[c] * (t[i] - stats[c * 2]) * stats[c * 2 + 1] + be[c], 0.f);
}

// ---------------- conv 3x3 stride 2 pad 1, 96->192 ----------------
__global__ __launch_bounds__(256) void k_conv(const float* __restrict__ s,
                                              const float* __restrict__ Wd,
                                              const float* __restrict__ bd,
                                              float* __restrict__ z) {
    __shared__ float Wl[96 * 9 * 16];
    int b = blockIdx.z;
    int oc0 = blockIdx.y * 16;
    int p = blockIdx.x * 256 + threadIdx.x;
    for (int i = threadIdx.x; i < 96 * 9 * 16; i += 256) {
        int oc = i & 15;
        int icq = i >> 4;
        Wl[i] = Wd[(size_t)(oc0 + oc) * 864 + icq];
    }
    __syncthreads();
    if (p >= NO_) return;
    int oh = p / HO_, ow = p % HO_;
    float acc[16];
#pragma unroll
    for (int i = 0; i < 16; i++) acc[i] = 0.f;
    int ih0 = oh * 2 - 1, iw0 = ow * 2 - 1;
    const float* sb = s + (size_t)b * C_ * N_;
    for (int ic = 0; ic < 96; ++ic) {
        const float* sp = sb + (size_t)ic * N_;
        float in[9];
#pragma unroll
        for (int kh = 0; kh < 3; kh++) {
            int ih = ih0 + kh;
            bool okh = (unsigned)ih < 56u;
#pragma unroll
            for (int kw = 0; kw < 3; kw++) {
                int iw = iw0 + kw;
                bool ok = okh && ((unsigned)iw < 56u);
                in[kh * 3 + kw] = ok ? sp[ih * 56 + iw] : 0.f;
            }
        }
#pragma unroll
        for (int q = 0; q < 9; q++) {
            float iv = in[q];
            const float4* w4 = (const float4*)&Wl[(ic * 9 + q) * 16];
#pragma unroll
            for (int j = 0; j < 4; j++) {
                float4 w = w4[j];
                acc[j * 4 + 0] += iv * w.x;
                acc[j * 4 + 1] += iv * w.y;
                acc[j * 4 + 2] += iv * w.z;
                acc[j * 4 + 3] += iv * w.w;
            }
        }
    }
#pragma unroll
    for (int i = 0; i < 16; i++)
        z[((size_t)b * OUP_ + oc0 + i) * NO_ + p] = acc[i] + bd[oc0 + i];
}

// ---------------- out = relu(dwbn(z)) ----------------
__global__ __launch_bounds__(256) void k_out(const float* __restrict__ z,
                                             const float* __restrict__ stats,
                                             const float* __restrict__ g,
                                             const float* __restrict__ be,
                                             float* __restrict__ out) {
    int i = blockIdx.x * 256 + threadIdx.x;
    if (i >= B_ * OUP_ * NO_) return;
    int c = (i / NO_) % OUP_;
    out[i] = fmaxf(g[c] * (z[i] - stats[c * 2]) * stats[c * 2 + 1] + be[c], 0.f);
}

extern "C" void kernel_launch(void* const* d_in, const int* in_sizes, int n_in,
                              void* d_out, int out_size, void* d_ws, size_t ws_size,
                              hipStream_t stream) {
    const float* x     = (const float*)d_in[0];
    const float* W_fc1 = (const float*)d_in[1];
    const float* b_fc1 = (const float*)d_in[2];
    const float* g_bn1 = (const float*)d_in[3];
    const float* be_bn1= (const float*)d_in[4];
    const float* W_edge= (const float*)d_in[5];
    const float* b_edge= (const float*)d_in[6];
    const float* g_bne = (const float*)d_in[7];
    const float* be_bne= (const float*)d_in[8];
    const float* W_fc2 = (const float*)d_in[9];
    const float* b_fc2 = (const float*)d_in[10];
    const float* g_bn2 = (const float*)d_in[11];
    const float* be_bn2= (const float*)d_in[12];
    const float* g_sabn= (const float*)d_in[13];
    const float* be_sabn=(const float*)d_in[14];
    const float* W_dw  = (const float*)d_in[15];
    const float* b_dw  = (const float*)d_in[16];
    const float* g_dwbn= (const float*)d_in[17];
    const float* be_dwbn=(const float*)d_in[18];

    // byte-offset workspace layout with lifetime-based aliasing (~77 MB)
    char* base = (char*)d_ws;
    float*  ftc   = (float*)(base + 0);                    //  9,633,792  [bn1 -> gemm_uv]; then sbuf
    float*  ftp32 = (float*)(base + 9633792);              //  9,633,792  [bn1 -> split];   then tbuf
    double* ftp64 = (double*)(base + 19267584);            // 19,267,584  [bn1 -> rerank];  then uu
    double* sq64  = (double*)(base + 38535168);            //    200,704
    double* yd    = (double*)(base + 38735872);            // 19,267,584  [fc1 -> bn1]
    unsigned short* fsp = (unsigned short*)(base + 38735872); // 10,035,200 [split -> dist] (aliases yd)
    float*  out2  = (float*)(base + 38735872);             //  9,633,792  [edge_fc2 -> bn2] (aliases fsp)
    unsigned short* poolC = (unsigned short*)(base + 48771072); // 2,007,040 [dist -> rerank]
    float*  zbuf  = (float*)(base + 48771072);             //  4,816,896  [conv -> out] (aliases poolC)
    int*    idx   = (int*)(base + 55193600);               //    903,168  [rerank -> edge]
    float*  uu    = (float*)(base + 19267584);             // 19,267,584  [gemm -> edge_fc2] (aliases ftp64, after rerank)
    float*  vv    = (float*)(base + 56096768);             // 19,267,584  [gemm -> edge_fc2]
    float*  tbuf  = (float*)(base + 9633792);              //  [bn2 -> sabn]  (aliases ftp32)
    float*  sbuf  = (float*)(base + 0);                    //  [sabn -> conv] (aliases ftc)
    float*  partial = (float*)(base + 75364352);           //  1,204,224 max [bne_stats etc.]
    double* partiald = (double*)(base + 75364352);         //     24,576 (earlier use, same region)
    double* stats1d = (double*)(base + 76568576);
    float*  statsE  = (float*)(base + 76570112);
    float*  stats2  = (float*)(base + 76571648);
    float*  statsS  = (float*)(base + 76573184);
    float*  statsD  = (float*)(base + 76574720);
    float*  sq32    = (float*)(base + 76576256);           //    100,352
    unsigned* poolCnt = (unsigned*)(base + 76676608);      //    100,352 -> ends 76,776,960

    // fc1 + BN1 (fp64 path, exact stats + features)
    k_fc1_d<<<dim3(98, 2), 512, 0, stream>>>(x, W_fc1, b_fc1, yd);
    k_stats_chan_d<<<dim3(96, 16), 256, 0, stream>>>(yd, partiald);
    k_stats_reduce_d<<<1, 256, 0, stream>>>(partiald, stats1d);
    k_bn1_apply_d<<<9408, 256, 0, stream>>>(yd, stats1d, g_bn1, be_bn1, ftc, ftp32, ftp64);
    k_sqrows_d<<<98, 256, 0, stream>>>(ftp64, sq64, sq32);

    // kNN: split-bf16 MFMA + reg-resident threshold/compaction -> pool, fp64 re-rank -> exact top-9
    k_split<<<1176, 256, 0, stream>>>(ftp32, fsp);
    k_dist2<<<dim3(49, B_), 256, 0, stream>>>(fsp, sq32, poolC, poolCnt);
    k_rerank_d<<<6272, 256, 0, stream>>>(poolC, poolCnt, ftp64, sq64, idx);

    // edge GEMM decomposition: u = ft·(Wtop-Wbot)+b_edge, v = ft·Wbot (uu overwrites ftp64 after rerank)
    k_gemm_uv<<<dim3(98, 4), 512, 0, stream>>>(ftc, W_edge, b_edge, uu, 0);
    k_gemm_uv<<<dim3(98, 4), 512, 0, stream>>>(ftc, W_edge, b_edge, vv, 1);

    // edge BN stats, then BN+relu+max+fc2
    k_bne_stats<<<784, 192, 0, stream>>>(uu, vv, idx, partial);
    k_stats_reduce_b2<<<192, 256, 0, stream>>>(partial, statsE, 1.0f / 225792.0f);
    k_edge_fc2<<<1568, 192, 0, stream>>>(uu, vv, idx, statsE, g_bne, be_bne, W_fc2, b_fc2, out2);

    // BN2 + shortcut
    k_stats_chan<<<dim3(96, 16), 256, 0, stream>>>(out2, partial, 96, N_, R_);
    k_stats_reduce<<<1, 256, 0, stream>>>(partial, stats2, 96, 16, 1.0f / (float)R_);
    k_bn2_add<<<9408, 256, 0, stream>>>(out2, x, stats2, g_bn2, be_bn2, tbuf);

    // sabn + relu
    k_stats_chan<<<dim3(96, 16), 256, 0, stream>>>(tbuf, partial, 96, N_, R_);
    k_stats_reduce<<<1, 256, 0, stream>>>(partial, statsS, 96, 16, 1.0f / (float)R_);
    k_sabn_relu<<<9408, 256, 0, stream>>>(tbuf, statsS, g_sabn, be_sabn, sbuf);

    // conv + dwbn + relu
    k_conv<<<dim3(4, 12, 8), 256, 0, stream>>>(sbuf, W_dw, b_dw, zbuf);
    k_stats_chan<<<dim3(192, 8), 256, 0, stream>>>(zbuf, partial, 192, NO_, 6272);
    k_stats_reduce<<<1, 256, 0, stream>>>(partial, statsD, 192, 8, 1.0f / 6272.0f);
    k_out<<<4705, 256, 0, stream>>>(zbuf, statsD, g_dwbn, be_dwbn, (float*)d_out);
}

// Round 7
// 649.644 us; speedup vs baseline: 1.6098x; 1.3695x over previous
//
#include <hip/hip_runtime.h>
#include <math.h>

#define B_   8
#define C_   96
#define C2_  192
#define N_   3136        // 56*56
#define R_   25088       // B_*N_
#define OUP_ 192
#define HO_  28
#define NO_  784         // 28*28
#define EPS_ 1e-5f
#define QSTR 104         // hi-only padded point stride (u16), 208 B = 13 x 16 B
#define CAP3 64          // per-row candidate pool cap

typedef short bf16x8 __attribute__((ext_vector_type(8)));
typedef float f32x4  __attribute__((ext_vector_type(4)));

// ---------------- fc1 (fp64 accumulate): yd[b,d,n] = sum_c x[b,c,n]*W1[c,d] + b1[d] ----------------
__global__ __launch_bounds__(512) void k_fc1_d(const float* __restrict__ x,
                                               const float* __restrict__ W1,
                                               const float* __restrict__ b1,
                                               double* __restrict__ yd) {
    __shared__ double Wl[96 * 48];
    int tid = threadIdx.x;
    int rl = tid & 255, h = tid >> 8;
    int dbase = blockIdx.y * 48;
    for (int q = tid; q < 96 * 48; q += 512) {
        int c = q / 48, dd = q % 48;
        Wl[c * 48 + dd] = (double)W1[c * 96 + dbase + dd];
    }
    __syncthreads();
    int r = blockIdx.x * 256 + rl;
    int b = r / N_;
    int n = r - b * N_;
    double acc[24];
#pragma unroll
    for (int i = 0; i < 24; i++) acc[i] = 0.0;
    const float* xp = x + (size_t)b * C_ * N_ + n;
    for (int c = 0; c < 96; ++c) {
        double xv = (double)xp[(size_t)c * N_];
        const double* w = &Wl[c * 48 + h * 24];
#pragma unroll
        for (int i = 0; i < 24; ++i) acc[i] += xv * w[i];
    }
    int d0 = dbase + h * 24;
#pragma unroll
    for (int i = 0; i < 24; i++) {
        int d = d0 + i;
        yd[((size_t)b * C_ + d) * N_ + n] = acc[i] + (double)b1[d];
    }
}

// ---------------- fp64 per-channel stats over yd ----------------
__global__ __launch_bounds__(256) void k_stats_chan_d(const double* __restrict__ src,
                                                      double* __restrict__ partial) {
    int c = blockIdx.x;
    int chunk = blockIdx.y;
    const int SPLIT = 16;
    double s = 0.0, ss = 0.0;
    for (int j = chunk * 256 + threadIdx.x; j < R_; j += SPLIT * 256) {
        int b = j / N_, n = j - b * N_;
        double v = src[((size_t)b * C_ + c) * N_ + n];
        s += v;
        ss += v * v;
    }
    __shared__ double red[8];
    for (int off = 32; off; off >>= 1) {
        s += __shfl_down(s, off, 64);
        ss += __shfl_down(ss, off, 64);
    }
    int lane = threadIdx.x & 63, w = threadIdx.x >> 6;
    if (lane == 0) { red[w * 2] = s; red[w * 2 + 1] = ss; }
    __syncthreads();
    if (threadIdx.x == 0) {
        s = red[0] + red[2] + red[4] + red[6];
        ss = red[1] + red[3] + red[5] + red[7];
        partial[(c * SPLIT + chunk) * 2] = s;
        partial[(c * SPLIT + chunk) * 2 + 1] = ss;
    }
}

__global__ void k_stats_reduce_d(const double* __restrict__ partial, double* __restrict__ stats) {
    int c = blockIdx.x * blockDim.x + threadIdx.x;
    if (c >= 96) return;
    double s = 0.0, ss = 0.0;
    for (int k = 0; k < 16; k++) {
        s += partial[(c * 16 + k) * 2];
        ss += partial[(c * 16 + k) * 2 + 1];
    }
    double m = s / (double)R_;
    double var = ss / (double)R_ - m * m;
    stats[c * 2] = m;
    stats[c * 2 + 1] = 1.0 / sqrt(var + 1e-5);
}

// ---------------- fp32 per-channel stats ----------------
__global__ __launch_bounds__(256) void k_stats_chan(const float* __restrict__ src,
                                                    float* __restrict__ partial,
                                                    int Cn, int Nsp, int total) {
    int c = blockIdx.x;
    int chunk = blockIdx.y;
    int SPLIT = gridDim.y;
    float s = 0.f, ss = 0.f;
    for (int j = chunk * 256 + threadIdx.x; j < total; j += SPLIT * 256) {
        int b = j / Nsp, n = j - b * Nsp;
        float v = src[((size_t)b * Cn + c) * Nsp + n];
        s += v;
        ss += v * v;
    }
    __shared__ float red[8];
    for (int off = 32; off; off >>= 1) {
        s += __shfl_down(s, off, 64);
        ss += __shfl_down(ss, off, 64);
    }
    int lane = threadIdx.x & 63, w = threadIdx.x >> 6;
    if (lane == 0) { red[w * 2] = s; red[w * 2 + 1] = ss; }
    __syncthreads();
    if (threadIdx.x == 0) {
        s = red[0] + red[2] + red[4] + red[6];
        ss = red[1] + red[3] + red[5] + red[7];
        partial[(c * SPLIT + chunk) * 2] = s;
        partial[(c * SPLIT + chunk) * 2 + 1] = ss;
    }
}

__global__ void k_stats_reduce(const float* __restrict__ partial, float* __restrict__ stats,
                               int Cn, int SPLIT, float invcount) {
    int c = blockIdx.x * blockDim.x + threadIdx.x;
    if (c >= Cn) return;
    float s = 0.f, ss = 0.f;
    for (int k = 0; k < SPLIT; k++) {
        s += partial[(c * SPLIT + k) * 2];
        ss += partial[(c * SPLIT + k) * 2 + 1];
    }
    float m = s * invcount;
    float var = ss * invcount - m * m;
    stats[c * 2] = m;
    stats[c * 2 + 1] = 1.0f / sqrtf(var + EPS_);
}

// parallel reduce for k_bne_stats partials: one block per channel
__global__ __launch_bounds__(256) void k_stats_reduce_b2(const float* __restrict__ partial,
                                                         float* __restrict__ stats,
                                                         float invcount) {
    int c = blockIdx.x;      // 0..191
    float s = 0.f, ss = 0.f;
    for (int k = threadIdx.x; k < 784; k += 256) {
        s  += partial[(size_t)k * 384 + c];
        ss += partial[(size_t)k * 384 + 192 + c];
    }
    __shared__ float red[8];
    for (int off = 32; off; off >>= 1) {
        s += __shfl_down(s, off, 64);
        ss += __shfl_down(ss, off, 64);
    }
    int lane = threadIdx.x & 63, w = threadIdx.x >> 6;
    if (lane == 0) { red[w * 2] = s; red[w * 2 + 1] = ss; }
    __syncthreads();
    if (threadIdx.x == 0) {
        s = red[0] + red[2] + red[4] + red[6];
        ss = red[1] + red[3] + red[5] + red[7];
        float m = s * invcount;
        float var = ss * invcount - m * m;
        stats[c * 2] = m;
        stats[c * 2 + 1] = 1.0f / sqrtf(var + EPS_);
    }
}

// ---------------- apply BN1 (fp64); emit ftc (f32 ch-major), ftp32/ftp64 (point-major) ----------------
__global__ __launch_bounds__(256) void k_bn1_apply_d(const double* __restrict__ yd,
                                                     const double* __restrict__ stats,
                                                     const float* __restrict__ g,
                                                     const float* __restrict__ be,
                                                     float* __restrict__ ftc,
                                                     float* __restrict__ ftp32,
                                                     double* __restrict__ ftp64) {
    int i = blockIdx.x * 256 + threadIdx.x;
    if (i >= B_ * C_ * N_) return;
    int n = i % N_;
    int bc = i / N_;
    int c = bc % C_;
    int b = bc / C_;
    double m = stats[c * 2], rs = stats[c * 2 + 1];
    double v = (double)g[c] * (yd[i] - m) * rs + (double)be[c];
    float vf = (float)v;
    ftc[i] = vf;
    size_t pp = ((size_t)b * N_ + n) * C_ + c;
    ftp32[pp] = vf;
    ftp64[pp] = v;
}

// ---------------- row squared norms: fp64 exact + fp32 copy ----------------
__global__ __launch_bounds__(256) void k_sqrows_d(const double* __restrict__ ftp64,
                                                  double* __restrict__ sq64,
                                                  float* __restrict__ sq32) {
    int r = blockIdx.x * 256 + threadIdx.x;
    if (r >= R_) return;
    const double* p = ftp64 + (size_t)r * C_;
    double s = 0.0;
    for (int q = 0; q < 96; q++) s += p[q] * p[q];
    sq64[r] = s;
    sq32[r] = (float)s;
}

// ---------------- split ft into bf16 hi halves (point-major, padded stride 104) ----------------
__global__ __launch_bounds__(256) void k_split_h(const float* __restrict__ ftp32,
                                                 unsigned short* __restrict__ fspH) {
    int t = blockIdx.x * 256 + threadIdx.x;
    if (t >= R_ * 12) return;
    int p = t / 12, g = t % 12;
    const float* src = ftp32 + (size_t)p * C_ + g * 8;
    unsigned short hi[8];
#pragma unroll
    for (int j = 0; j < 8; ++j) {
        unsigned u = __float_as_uint(src[j]);
        hi[j] = (unsigned short)((u + 0x7fffu + ((u >> 16) & 1u)) >> 16);   // RNE to bf16
    }
    unsigned short* dh = fspH + (size_t)p * QSTR + g * 8;
    *(ushort4*)dh       = *(ushort4*)&hi[0];
    *(ushort4*)(dh + 4) = *(ushort4*)&hi[4];
}

// ---------------- swapped-operand hi-bf16 MFMA distance, 2-pass threshold + compaction ----------------
// block = 64 queries (q0..q0+63) x all 3136 candidates (49 chunks of 64); 4 waves.
// D[cand][query] = mfma(A=cand tile from LDS, B=query frags in regs): per-query chunk-min is
// 15 reg-min + 2 shfl_xor. Double-buffered chunk staging (issue-early / write-late, 1 barrier/chunk).
// pass 0: per-query 64-cand chunk minima (49/query) -> t16 = 16th smallest (provable >=16 bound)
// pass 1: compact cands with d <= t16 + 1% + 1.0 into per-query pool (fp64 re-rank restores exactness)
__global__ __launch_bounds__(256) void k_dist3(const unsigned short* __restrict__ fspH,
                                               const float* __restrict__ sq32,
                                               unsigned short* __restrict__ poolC,
                                               unsigned* __restrict__ poolCnt) {
    __shared__ __align__(16) char lds[42112];
    // [0,13312) Bl buf0 | [13312,26624) Bl buf1 | [26624,39936) query staging (dead early)
    // aliases after staging: cminL u16 49x64 @26624 ; poolL u16 64x64 @32896
    // cntL u32[64] @41088 ; t16fL f32[64] @41344 ; sqtl f32[2][64] @41600
    unsigned short* cminL = (unsigned short*)(lds + 26624);
    unsigned short* poolL = (unsigned short*)(lds + 32896);
    unsigned*       cntL  = (unsigned*)(lds + 41088);
    float*          t16fL = (float*)(lds + 41344);

    int b = blockIdx.y;
    int q0 = blockIdx.x * 64;
    int tid = threadIdx.x;
    int w = tid >> 6, l = tid & 63;
    const int koff = (l >> 4) * 8;

    // stage queries (64 x 208 B) then load query B-frags to registers
    {
        const uint4* src = (const uint4*)(fspH + ((size_t)b * N_ + q0) * QSTR);
        uint4* dst = (uint4*)(lds + 26624);
        for (int i = tid; i < 832; i += 256) dst[i] = src[i];
    }
    __syncthreads();
    bf16x8 Bq[3];
    {
        const unsigned short* Ql = (const unsigned short*)(lds + 26624);
#pragma unroll
        for (int s = 0; s < 3; ++s)
            Bq[s] = *(const bf16x8*)&Ql[(w * 16 + (l & 15)) * QSTR + s * 32 + koff];
    }
    __syncthreads();   // query staging dead; cmin/pool regions free

    // prologue: stage chunk 0 into buffer 0
    {
        const uint4* src = (const uint4*)(fspH + ((size_t)b * N_) * QSTR);
        uint4* dst = (uint4*)lds;
#pragma unroll
        for (int k = 0; k < 4; ++k) { int i = tid + k * 256; if (i < 832) dst[i] = src[i]; }
        if (tid < 64) ((float*)(lds + 41600))[tid] = sq32[(size_t)b * N_ + tid];
    }
    __syncthreads();

    float t16r = 0.f;
    int cur = 0;
    for (int t = 0; t < 98; ++t) {
        int ch = (t < 49) ? t : t - 49;
        int c0 = ch * 64;
        bool pf = (t < 97);
        uint4 st0, st1, st2, st3; float sqst = 0.f;
        if (pf) {
            int nch = (t + 1 < 49) ? (t + 1) : (t + 1 - 49);
            const uint4* src = (const uint4*)(fspH + ((size_t)b * N_ + nch * 64) * QSTR);
            st0 = src[tid];
            st1 = src[tid + 256];
            st2 = src[tid + 512];
            if (tid < 64) { st3 = src[tid + 768]; sqst = sq32[(size_t)b * N_ + nch * 64 + tid]; }
        }
        // compute on current buffer
        const unsigned short* Bc = (const unsigned short*)(lds + cur * 13312);
        const float* sqc = (const float*)(lds + 41600 + cur * 256);
        f32x4 acc[4];
#pragma unroll
        for (int ct = 0; ct < 4; ++ct) acc[ct] = (f32x4){0.f, 0.f, 0.f, 0.f};
#pragma unroll
        for (int s = 0; s < 3; ++s) {
#pragma unroll
            for (int ct = 0; ct < 4; ++ct) {
                bf16x8 Ac = *(const bf16x8*)&Bc[(ct * 16 + (l & 15)) * QSTR + s * 32 + koff];
                acc[ct] = __builtin_amdgcn_mfma_f32_16x16x32_bf16(Ac, Bq[s], acc[ct], 0, 0, 0);
            }
        }
        f32x4 scn[4];
#pragma unroll
        for (int ct = 0; ct < 4; ++ct) scn[ct] = *(const f32x4*)&sqc[ct * 16 + (l >> 4) * 4];
        if (t < 49) {
            // per-query min over this chunk's 64 candidates (query-norm dropped: order-invariant)
            float m = 1e30f;
#pragma unroll
            for (int ct = 0; ct < 4; ++ct)
#pragma unroll
                for (int j = 0; j < 4; ++j)
                    m = fminf(m, fmaf(-2.f, acc[ct][j], scn[ct][j]));
            m = fminf(m, __shfl_xor(m, 16, 64));
            m = fminf(m, __shfl_xor(m, 32, 64));
            if (l < 16) {
                unsigned u = __float_as_uint(m);
                unsigned ku = u ^ (0x80000000u | (unsigned)((int)u >> 31));   // monotone key
                cminL[ch * 64 + w * 16 + l] = (unsigned short)(ku >> 16);
            }
        } else {
            int qrow = w * 16 + (l & 15);
#pragma unroll
            for (int ct = 0; ct < 4; ++ct)
#pragma unroll
                for (int j = 0; j < 4; ++j) {
                    float d = fmaf(-2.f, acc[ct][j], scn[ct][j]);
                    if (d <= t16r) {                                          // rare
                        unsigned pos = atomicAdd(&cntL[qrow], 1u);
                        if (pos < (unsigned)CAP3)
                            poolL[qrow * CAP3 + pos] = (unsigned short)(c0 + ct * 16 + (l >> 4) * 4 + j);
                    }
                }
        }
        if (t == 48) {
            __syncthreads();       // all cmin written
            if (tid < 64) {
                unsigned short top[16];
#pragma unroll
                for (int j = 0; j < 16; ++j) top[j] = 0xFFFFu;
                for (int q = 0; q < 49; ++q) {
                    unsigned short v = cminL[q * 64 + tid];
                    if (v < top[15]) {
                        top[15] = v;
#pragma unroll
                        for (int j = 15; j >= 1; --j)
                            if (top[j] < top[j - 1]) { unsigned short tt = top[j]; top[j] = top[j - 1]; top[j - 1] = tt; }
                    }
                }
                unsigned ku = ((unsigned)top[15] << 16) | 0xFFFFu;   // bucket upper bound
                float f = (ku & 0x80000000u) ? __uint_as_float(ku ^ 0x80000000u)
                                             : __uint_as_float(~ku);
                t16fL[tid] = f + fabsf(f) * 0.01f + 1.0f;            // safe hi-bf16 error inflation
                cntL[tid] = 0u;
            }
            __syncthreads();
            t16r = t16fL[w * 16 + (l & 15)];
        }
        if (pf) {
            uint4* dst = (uint4*)(lds + (cur ^ 1) * 13312);
            dst[tid] = st0;
            dst[tid + 256] = st1;
            dst[tid + 512] = st2;
            if (tid < 64) { dst[tid + 768] = st3; ((float*)(lds + 41600 + (cur ^ 1) * 256))[tid] = sqst; }
        }
        __syncthreads();
        cur ^= 1;
    }
    if (tid < 64) {
        unsigned c = cntL[tid];
        poolCnt[(size_t)b * N_ + q0 + tid] = (c > (unsigned)CAP3) ? (unsigned)CAP3 : c;
    }
    {
        unsigned* dst = (unsigned*)(poolC + ((size_t)b * N_ + q0) * CAP3);
        const unsigned* src = (const unsigned*)poolL;
        for (int i = tid; i < 64 * CAP3 / 2; i += 256) dst[i] = src[i];
    }
}

// ---------------- fp64 exact re-rank of variable pool -> top-9 set ----------------
// one wave per row; one lane per pool candidate; 9 lexicographic wave-min extractions
__global__ __launch_bounds__(256) void k_rerank_d(const unsigned short* __restrict__ poolC,
                                                  const unsigned* __restrict__ poolCnt,
                                                  const double* __restrict__ ftp64,
                                                  const double* __restrict__ sq64,
                                                  int* __restrict__ idx) {
    int tid = threadIdx.x;
    int wv = tid >> 6, l = tid & 63;
    int rr = blockIdx.x * 4 + wv;
    int b = rr / N_;
    unsigned cnt = poolCnt[rr];
    if (cnt > (unsigned)CAP3) cnt = CAP3;
    double d = 1e300;
    int j = 0x7fffffff;
    if (l < (int)cnt) {
        j = (int)poolC[(size_t)rr * CAP3 + l];
        const double* qb = ftp64 + (size_t)rr * C_;
        const double* cb = ftp64 + ((size_t)b * N_ + j) * C_;
        double s0 = 0.0, s1 = 0.0;
#pragma unroll
        for (int k = 0; k < 96; k += 2) {
            s0 += qb[k] * cb[k];
            s1 += qb[k + 1] * cb[k + 1];
        }
        d = sq64[(size_t)b * N_ + j] - 2.0 * (s0 + s1);   // per-row sqn dropped
    }
#pragma unroll
    for (int r = 0; r < 9; ++r) {
        double dm = d;
        int jm = j;
#pragma unroll
        for (int off = 1; off <= 32; off <<= 1) {
            double od = __shfl_xor(dm, off, 64);
            int oj = __shfl_xor(jm, off, 64);
            if (od < dm || (od == dm && oj < jm)) { dm = od; jm = oj; }
        }
        if (l == 0) idx[(size_t)rr * 9 + r] = jm;
        if (j == jm) d = 1e300;    // retire winner (j unique per lane)
    }
}

// ---------------- u = ft·(Wtop-Wbot) + b_edge (mode 0), v = ft·Wbot (mode 1) ----------------
__global__ __launch_bounds__(512) void k_gemm_uv(const float* __restrict__ ftc,
                                                 const float* __restrict__ We,
                                                 const float* __restrict__ beb,
                                                 float* __restrict__ out, int mode) {
    __shared__ float Wl[96 * 48];
    int tid = threadIdx.x;
    int rl = tid & 255, h = tid >> 8;
    int dbase = blockIdx.y * 48;
    for (int q = tid; q < 96 * 48; q += 512) {
        int c = q / 48, dd = q % 48;
        float w = We[(96 + c) * C2_ + dbase + dd];
        if (mode == 0) w = We[c * C2_ + dbase + dd] - w;
        Wl[c * 48 + dd] = w;
    }
    __syncthreads();
    int r = blockIdx.x * 256 + rl;
    int b = r / N_, n = r - b * N_;
    float acc[24];
#pragma unroll
    for (int i = 0; i < 24; i++) acc[i] = 0.f;
    const float* xp = ftc + (size_t)b * C_ * N_ + n;
    for (int c = 0; c < 96; ++c) {
        float xv = xp[(size_t)c * N_];
        const float4* w4 = (const float4*)&Wl[c * 48 + h * 24];
#pragma unroll
        for (int i = 0; i < 6; ++i) {
            float4 w = w4[i];
            acc[i * 4 + 0] += xv * w.x;
            acc[i * 4 + 1] += xv * w.y;
            acc[i * 4 + 2] += xv * w.z;
            acc[i * 4 + 3] += xv * w.w;
        }
    }
    int d0 = dbase + h * 24;
    float* op = out + (size_t)r * C2_ + d0;
#pragma unroll
    for (int i = 0; i < 6; ++i) {
        float4 o;
        o.x = acc[i * 4 + 0]; o.y = acc[i * 4 + 1];
        o.z = acc[i * 4 + 2]; o.w = acc[i * 4 + 3];
        if (mode == 0) {
            o.x += beb[d0 + i * 4 + 0];
            o.y += beb[d0 + i * 4 + 1];
            o.z += beb[d0 + i * 4 + 2];
            o.w += beb[d0 + i * 4 + 3];
        }
        ((float4*)op)[i] = o;
    }
}

// ---------------- edge-BN stats: e = u[n,d] + v[j,d] over all (row,k) ----------------
__global__ __launch_bounds__(192) void k_bne_stats(const float* __restrict__ u,
                                                   const float* __restrict__ v,
                                                   const int* __restrict__ idx,
                                                   float* __restrict__ partial) {
    int d = threadIdx.x;
    int row0 = blockIdx.x * 32;
    int b = row0 / N_;
    float s = 0.f, ss = 0.f;
    for (int r = 0; r < 32; ++r) {
        int row = row0 + r;
        float ud = u[(size_t)row * C2_ + d];
        const int* ip = idx + (size_t)row * 9;
#pragma unroll
        for (int k = 0; k < 9; k++) {
            int j = ip[k];
            float e = ud + v[((size_t)b * N_ + j) * C2_ + d];
            s += e;
            ss += e * e;
        }
    }
    partial[(size_t)blockIdx.x * 384 + d] = s;
    partial[(size_t)blockIdx.x * 384 + 192 + d] = ss;
}

// ---------------- edge BN+relu+max over k, then fc2 (192->96) ----------------
__global__ __launch_bounds__(192) void k_edge_fc2(const float* __restrict__ u,
                                                  const float* __restrict__ v,
                                                  const int* __restrict__ idx,
                                                  const float* __restrict__ statsE,
                                                  const float* __restrict__ ge,
                                                  const float* __restrict__ bee,
                                                  const float* __restrict__ W2,
                                                  const float* __restrict__ b2,
                                                  float* __restrict__ out2) {
    __shared__ float gl[16][C2_];
    __shared__ float g2[C_][16];
    int tid = threadIdx.x;
    int row0 = blockIdx.x * 16;
    int b = row0 / N_;
    int n0 = row0 - b * N_;
    {
        int d = tid;
        float m = statsE[d * 2], rs = statsE[d * 2 + 1];
        float ga = ge[d], bb = bee[d];
        for (int r = 0; r < 16; ++r) {
            int row = row0 + r;
            float ud = u[(size_t)row * C2_ + d];
            const int* ip = idx + (size_t)row * 9;
            float gm = 0.f;                      // relu-then-max == max with 0
#pragma unroll
            for (int k = 0; k < 9; k++) {
                int j = ip[k];
                float e = ud + v[((size_t)b * N_ + j) * C2_ + d];
                float val = ga * (e - m) * rs + bb;
                gm = fmaxf(gm, val);
            }
            gl[r][d] = gm;
        }
    }
    __syncthreads();
    {
        int rr = tid / 24;
        int dq = tid % 24;
        for (int rep = 0; rep < 2; ++rep) {
            int r = rr + rep * 8;
            float4 acc = *(const float4*)&b2[dq * 4];
            for (int d = 0; d < C2_; ++d) {
                float gv = gl[r][d];
                float4 w = *(const float4*)&W2[d * C_ + dq * 4];
                acc.x += gv * w.x;
                acc.y += gv * w.y;
                acc.z += gv * w.z;
                acc.w += gv * w.w;
            }
            g2[dq * 4 + 0][r] = acc.x;
            g2[dq * 4 + 1][r] = acc.y;
            g2[dq * 4 + 2][r] = acc.z;
            g2[dq * 4 + 3][r] = acc.w;
        }
    }
    __syncthreads();
    for (int q = tid; q < 96 * 4; q += 192) {
        int dd = q / 4, part = q % 4;
        float4 val = *(const float4*)&g2[dd][part * 4];
        *(float4*)&out2[((size_t)b * C_ + dd) * N_ + n0 + part * 4] = val;
    }
}

// ---------------- t = bn2(out2) + x ----------------
__global__ __launch_bounds__(256) void k_bn2_add(const float* __restrict__ out2,
                                                 const float* __restrict__ x,
                                                 const float* __restrict__ stats,
                                                 const float* __restrict__ g,
                                                 const float* __restrict__ be,
                                                 float* __restrict__ t) {
    int i = blockIdx.x * 256 + threadIdx.x;
    if (i >= B_ * C_ * N_) return;
    int c = (i / N_) % C_;
    t[i] = g[c] * (out2[i] - stats[c * 2]) * stats[c * 2 + 1] + be[c] + x[i];
}

// ---------------- s = relu(sabn(t)) ----------------
__global__ __launch_bounds__(256) void k_sabn_relu(const float* __restrict__ t,
                                                   const float* __restrict__ stats,
                                                   const float* __restrict__ g,
                                                   const float* __restrict__ be,
                                                   float* __restrict__ s) {
    int i = blockIdx.x * 256 + threadIdx.x;
    if (i >= B_ * C_ * N_) return;
    int c = (i / N_) % C_;
    s[i] = fmaxf(g[c] * (t[i] - stats[c * 2]) * stats[c * 2 + 1] + be[c], 0.f);
}

// ---------------- conv 3x3 stride 2 pad 1, 96->192 ----------------
__global__ __launch_bounds__(256) void k_conv(const float* __restrict__ s,
                                              const float* __restrict__ Wd,
                                              const float* __restrict__ bd,
                                              float* __restrict__ z) {
    __shared__ float Wl[96 * 9 * 16];
    int b = blockIdx.z;
    int oc0 = blockIdx.y * 16;
    int p = blockIdx.x * 256 + threadIdx.x;
    for (int i = threadIdx.x; i < 96 * 9 * 16; i += 256) {
        int oc = i & 15;
        int icq = i >> 4;
        Wl[i] = Wd[(size_t)(oc0 + oc) * 864 + icq];
    }
    __syncthreads();
    if (p >= NO_) return;
    int oh = p / HO_, ow = p % HO_;
    float acc[16];
#pragma unroll
    for (int i = 0; i < 16; i++) acc[i] = 0.f;
    int ih0 = oh * 2 - 1, iw0 = ow * 2 - 1;
    const float* sb = s + (size_t)b * C_ * N_;
    for (int ic = 0; ic < 96; ++ic) {
        const float* sp = sb + (size_t)ic * N_;
        float in[9];
#pragma unroll
        for (int kh = 0; kh < 3; kh++) {
            int ih = ih0 + kh;
            bool okh = (unsigned)ih < 56u;
#pragma unroll
            for (int kw = 0; kw < 3; kw++) {
                int iw = iw0 + kw;
                bool ok = okh && ((unsigned)iw < 56u);
                in[kh * 3 + kw] = ok ? sp[ih * 56 + iw] : 0.f;
            }
        }
#pragma unroll
        for (int q = 0; q < 9; q++) {
            float iv = in[q];
            const float4* w4 = (const float4*)&Wl[(ic * 9 + q) * 16];
#pragma unroll
            for (int j = 0; j < 4; j++) {
                float4 w = w4[j];
                acc[j * 4 + 0] += iv * w.x;
                acc[j * 4 + 1] += iv * w.y;
                acc[j * 4 + 2] += iv * w.z;
                acc[j * 4 + 3] += iv * w.w;
            }
        }
    }
#pragma unroll
    for (int i = 0; i < 16; i++)
        z[((size_t)b * OUP_ + oc0 + i) * NO_ + p] = acc[i] + bd[oc0 + i];
}

// ---------------- out = relu(dwbn(z)) ----------------
__global__ __launch_bounds__(256) void k_out(const float* __restrict__ z,
                                             const float* __restrict__ stats,
                                             const float* __restrict__ g,
                                             const float* __restrict__ be,
                                             float* __restrict__ out) {
    int i = blockIdx.x * 256 + threadIdx.x;
    if (i >= B_ * OUP_ * NO_) return;
    int c = (i / NO_) % OUP_;
    out[i] = fmaxf(g[c] * (z[i] - stats[c * 2]) * stats[c * 2 + 1] + be[c], 0.f);
}

extern "C" void kernel_launch(void* const* d_in, const int* in_sizes, int n_in,
                              void* d_out, int out_size, void* d_ws, size_t ws_size,
                              hipStream_t stream) {
    const float* x     = (const float*)d_in[0];
    const float* W_fc1 = (const float*)d_in[1];
    const float* b_fc1 = (const float*)d_in[2];
    const float* g_bn1 = (const float*)d_in[3];
    const float* be_bn1= (const float*)d_in[4];
    const float* W_edge= (const float*)d_in[5];
    const float* b_edge= (const float*)d_in[6];
    const float* g_bne = (const float*)d_in[7];
    const float* be_bne= (const float*)d_in[8];
    const float* W_fc2 = (const float*)d_in[9];
    const float* b_fc2 = (const float*)d_in[10];
    const float* g_bn2 = (const float*)d_in[11];
    const float* be_bn2= (const float*)d_in[12];
    const float* g_sabn= (const float*)d_in[13];
    const float* be_sabn=(const float*)d_in[14];
    const float* W_dw  = (const float*)d_in[15];
    const float* b_dw  = (const float*)d_in[16];
    const float* g_dwbn= (const float*)d_in[17];
    const float* be_dwbn=(const float*)d_in[18];

    // byte-offset workspace layout with lifetime-based aliasing (~77 MB)
    char* base = (char*)d_ws;
    float*  ftc   = (float*)(base + 0);                    //  9,633,792  [bn1 -> gemm_uv]; then sbuf
    float*  ftp32 = (float*)(base + 9633792);              //  9,633,792  [bn1 -> split];   then tbuf
    double* ftp64 = (double*)(base + 19267584);            // 19,267,584  [bn1 -> rerank];  then uu
    double* sq64  = (double*)(base + 38535168);            //    200,704
    double* yd    = (double*)(base + 38735872);            // 19,267,584  [fc1 -> bn1]
    unsigned short* fspH = (unsigned short*)(base + 38735872); // 5,218,304 [split -> dist] (aliases yd)
    float*  out2  = (float*)(base + 38735872);             //  9,633,792  [edge_fc2 -> bn2] (aliases fspH)
    unsigned short* poolC = (unsigned short*)(base + 48771072); // 3,211,264 [dist -> rerank]
    float*  zbuf  = (float*)(base + 48771072);             //  4,816,896  [conv -> out] (aliases poolC)
    int*    idx   = (int*)(base + 55193600);               //    903,168  [rerank -> edge]
    float*  uu    = (float*)(base + 19267584);             // 19,267,584  [gemm -> edge_fc2] (aliases ftp64, after rerank)
    float*  vv    = (float*)(base + 56096768);             // 19,267,584  [gemm -> edge_fc2]
    float*  tbuf  = (float*)(base + 9633792);              //  [bn2 -> sabn]  (aliases ftp32)
    float*  sbuf  = (float*)(base + 0);                    //  [sabn -> conv] (aliases ftc)
    float*  partial = (float*)(base + 75364352);           //  1,204,224 max [bne_stats etc.]
    double* partiald = (double*)(base + 75364352);         //     24,576 (earlier use, same region)
    double* stats1d = (double*)(base + 76568576);
    float*  statsE  = (float*)(base + 76570112);
    float*  stats2  = (float*)(base + 76571648);
    float*  statsS  = (float*)(base + 76573184);
    float*  statsD  = (float*)(base + 76574720);
    float*  sq32    = (float*)(base + 76576256);           //    100,352
    unsigned* poolCnt = (unsigned*)(base + 76676608);      //    100,352 -> ends 76,776,960

    // fc1 + BN1 (fp64 path, exact stats + features)
    k_fc1_d<<<dim3(98, 2), 512, 0, stream>>>(x, W_fc1, b_fc1, yd);
    k_stats_chan_d<<<dim3(96, 16), 256, 0, stream>>>(yd, partiald);
    k_stats_reduce_d<<<1, 256, 0, stream>>>(partiald, stats1d);
    k_bn1_apply_d<<<9408, 256, 0, stream>>>(yd, stats1d, g_bn1, be_bn1, ftc, ftp32, ftp64);
    k_sqrows_d<<<98, 256, 0, stream>>>(ftp64, sq64, sq32);

    // kNN: swapped-operand hi-bf16 MFMA + threshold/compaction -> pool, fp64 re-rank -> exact top-9
    k_split_h<<<1176, 256, 0, stream>>>(ftp32, fspH);
    k_dist3<<<dim3(49, B_), 256, 0, stream>>>(fspH, sq32, poolC, poolCnt);
    k_rerank_d<<<6272, 256, 0, stream>>>(poolC, poolCnt, ftp64, sq64, idx);

    // edge GEMM decomposition: u = ft·(Wtop-Wbot)+b_edge, v = ft·Wbot (uu overwrites ftp64 after rerank)
    k_gemm_uv<<<dim3(98, 4), 512, 0, stream>>>(ftc, W_edge, b_edge, uu, 0);
    k_gemm_uv<<<dim3(98, 4), 512, 0, stream>>>(ftc, W_edge, b_edge, vv, 1);

    // edge BN stats, then BN+relu+max+fc2
    k_bne_stats<<<784, 192, 0, stream>>>(uu, vv, idx, partial);
    k_stats_reduce_b2<<<192, 256, 0, stream>>>(partial, statsE, 1.0f / 225792.0f);
    k_edge_fc2<<<1568, 192, 0, stream>>>(uu, vv, idx, statsE, g_bne, be_bne, W_fc2, b_fc2, out2);

    // BN2 + shortcut
    k_stats_chan<<<dim3(96, 16), 256, 0, stream>>>(out2, partial, 96, N_, R_);
    k_stats_reduce<<<1, 256, 0, stream>>>(partial, stats2, 96, 16, 1.0f / (float)R_);
    k_bn2_add<<<9408, 256, 0, stream>>>(out2, x, stats2, g_bn2, be_bn2, tbuf);

    // sabn + relu
    k_stats_chan<<<dim3(96, 16), 256, 0, stream>>>(tbuf, partial, 96, N_, R_);
    k_stats_reduce<<<1, 256, 0, stream>>>(partial, statsS, 96, 16, 1.0f / (float)R_);
    k_sabn_relu<<<9408, 256, 0, stream>>>(tbuf, statsS, g_sabn, be_sabn, sbuf);

    // conv + dwbn + relu
    k_conv<<<dim3(4, 12, 8), 256, 0, stream>>>(sbuf, W_dw, b_dw, zbuf);
    k_stats_chan<<<dim3(192, 8), 256, 0, stream>>>(zbuf, partial, 192, NO_, 6272);
    k_stats_reduce<<<1, 256, 0, stream>>>(partial, statsD, 192, 8, 1.0f / 6272.0f);
    k_out<<<4705, 256, 0, stream>>>(zbuf, statsD, g_dwbn, be_dwbn, (float*)d_out);
}

// Round 9
// 570.713 us; speedup vs baseline: 1.8324x; 1.1383x over previous
//
#include <hip/hip_runtime.h>
#include <math.h>

#define B_   8
#define C_   96
#define C2_  192
#define N_   3136        // 56*56
#define R_   25088       // B_*N_
#define OUP_ 192
#define HO_  28
#define NO_  784         // 28*28
#define EPS_ 1e-5f
#define QS2  128         // fspH point stride in u16 (256 B = 16 uint4)
#define CAP3 64          // per-row candidate pool cap

typedef short bf16x8 __attribute__((ext_vector_type(8)));
typedef float f32x4  __attribute__((ext_vector_type(4)));

// uint4-slot XOR swizzle within a 64-row x 16-col chunk tile (T2): col ^= row&7
__device__ __forceinline__ int swz16(int i) { return (i & ~15) | ((i & 15) ^ ((i >> 4) & 7)); }

// ---------------- fc1 (fp64 accumulate): yd[b,d,n] = sum_c x[b,c,n]*W1[c,d] + b1[d] ----------------
__global__ __launch_bounds__(512) void k_fc1_d(const float* __restrict__ x,
                                               const float* __restrict__ W1,
                                               const float* __restrict__ b1,
                                               double* __restrict__ yd) {
    __shared__ double Wl[96 * 48];
    int tid = threadIdx.x;
    int rl = tid & 255, h = tid >> 8;
    int dbase = blockIdx.y * 48;
    for (int q = tid; q < 96 * 48; q += 512) {
        int c = q / 48, dd = q % 48;
        Wl[c * 48 + dd] = (double)W1[c * 96 + dbase + dd];
    }
    __syncthreads();
    int r = blockIdx.x * 256 + rl;
    int b = r / N_;
    int n = r - b * N_;
    double acc[24];
#pragma unroll
    for (int i = 0; i < 24; i++) acc[i] = 0.0;
    const float* xp = x + (size_t)b * C_ * N_ + n;
    for (int c = 0; c < 96; ++c) {
        double xv = (double)xp[(size_t)c * N_];
        const double* w = &Wl[c * 48 + h * 24];
#pragma unroll
        for (int i = 0; i < 24; ++i) acc[i] += xv * w[i];
    }
    int d0 = dbase + h * 24;
#pragma unroll
    for (int i = 0; i < 24; i++) {
        int d = d0 + i;
        yd[((size_t)b * C_ + d) * N_ + n] = acc[i] + (double)b1[d];
    }
}

// ---------------- fp64 per-channel stats over yd ----------------
__global__ __launch_bounds__(256) void k_stats_chan_d(const double* __restrict__ src,
                                                      double* __restrict__ partial) {
    int c = blockIdx.x;
    int chunk = blockIdx.y;
    const int SPLIT = 16;
    double s = 0.0, ss = 0.0;
    for (int j = chunk * 256 + threadIdx.x; j < R_; j += SPLIT * 256) {
        int b = j / N_, n = j - b * N_;
        double v = src[((size_t)b * C_ + c) * N_ + n];
        s += v;
        ss += v * v;
    }
    __shared__ double red[8];
    for (int off = 32; off; off >>= 1) {
        s += __shfl_down(s, off, 64);
        ss += __shfl_down(ss, off, 64);
    }
    int lane = threadIdx.x & 63, w = threadIdx.x >> 6;
    if (lane == 0) { red[w * 2] = s; red[w * 2 + 1] = ss; }
    __syncthreads();
    if (threadIdx.x == 0) {
        s = red[0] + red[2] + red[4] + red[6];
        ss = red[1] + red[3] + red[5] + red[7];
        partial[(c * SPLIT + chunk) * 2] = s;
        partial[(c * SPLIT + chunk) * 2 + 1] = ss;
    }
}

__global__ void k_stats_reduce_d(const double* __restrict__ partial, double* __restrict__ stats) {
    int c = blockIdx.x * blockDim.x + threadIdx.x;
    if (c >= 96) return;
    double s = 0.0, ss = 0.0;
    for (int k = 0; k < 16; k++) {
        s += partial[(c * 16 + k) * 2];
        ss += partial[(c * 16 + k) * 2 + 1];
    }
    double m = s / (double)R_;
    double var = ss / (double)R_ - m * m;
    stats[c * 2] = m;
    stats[c * 2 + 1] = 1.0 / sqrt(var + 1e-5);
}

// ---------------- fp32 per-channel stats ----------------
__global__ __launch_bounds__(256) void k_stats_chan(const float* __restrict__ src,
                                                    float* __restrict__ partial,
                                                    int Cn, int Nsp, int total) {
    int c = blockIdx.x;
    int chunk = blockIdx.y;
    int SPLIT = gridDim.y;
    float s = 0.f, ss = 0.f;
    for (int j = chunk * 256 + threadIdx.x; j < total; j += SPLIT * 256) {
        int b = j / Nsp, n = j - b * Nsp;
        float v = src[((size_t)b * Cn + c) * Nsp + n];
        s += v;
        ss += v * v;
    }
    __shared__ float red[8];
    for (int off = 32; off; off >>= 1) {
        s += __shfl_down(s, off, 64);
        ss += __shfl_down(ss, off, 64);
    }
    int lane = threadIdx.x & 63, w = threadIdx.x >> 6;
    if (lane == 0) { red[w * 2] = s; red[w * 2 + 1] = ss; }
    __syncthreads();
    if (threadIdx.x == 0) {
        s = red[0] + red[2] + red[4] + red[6];
        ss = red[1] + red[3] + red[5] + red[7];
        partial[(c * SPLIT + chunk) * 2] = s;
        partial[(c * SPLIT + chunk) * 2 + 1] = ss;
    }
}

__global__ void k_stats_reduce(const float* __restrict__ partial, float* __restrict__ stats,
                               int Cn, int SPLIT, float invcount) {
    int c = blockIdx.x * blockDim.x + threadIdx.x;
    if (c >= Cn) return;
    float s = 0.f, ss = 0.f;
    for (int k = 0; k < SPLIT; k++) {
        s += partial[(c * SPLIT + k) * 2];
        ss += partial[(c * SPLIT + k) * 2 + 1];
    }
    float m = s * invcount;
    float var = ss * invcount - m * m;
    stats[c * 2] = m;
    stats[c * 2 + 1] = 1.0f / sqrtf(var + EPS_);
}

// parallel reduce for k_bne_stats partials: one block per channel
__global__ __launch_bounds__(256) void k_stats_reduce_b2(const float* __restrict__ partial,
                                                         float* __restrict__ stats,
                                                         float invcount) {
    int c = blockIdx.x;      // 0..191
    float s = 0.f, ss = 0.f;
    for (int k = threadIdx.x; k < 784; k += 256) {
        s  += partial[(size_t)k * 384 + c];
        ss += partial[(size_t)k * 384 + 192 + c];
    }
    __shared__ float red[8];
    for (int off = 32; off; off >>= 1) {
        s += __shfl_down(s, off, 64);
        ss += __shfl_down(ss, off, 64);
    }
    int lane = threadIdx.x & 63, w = threadIdx.x >> 6;
    if (lane == 0) { red[w * 2] = s; red[w * 2 + 1] = ss; }
    __syncthreads();
    if (threadIdx.x == 0) {
        s = red[0] + red[2] + red[4] + red[6];
        ss = red[1] + red[3] + red[5] + red[7];
        float m = s * invcount;
        float var = ss * invcount - m * m;
        stats[c * 2] = m;
        stats[c * 2 + 1] = 1.0f / sqrtf(var + EPS_);
    }
}

// ---------------- BN1 apply + LDS transpose: emit ftc (c-major f32), ftp64 (row-major, coalesced),
// fspH (bf16-hi, stride QS2), sq64/sq32 — all global accesses coalesced ----------------
__global__ __launch_bounds__(256) void k_bn1_tr(const double* __restrict__ yd,
                                                const double* __restrict__ stats,
                                                const float* __restrict__ g,
                                                const float* __restrict__ be,
                                                float* __restrict__ ftc,
                                                double* __restrict__ ftp64,
                                                unsigned short* __restrict__ fspH,
                                                double* __restrict__ sq64,
                                                float* __restrict__ sq32) {
    __shared__ double tile[64 * 97];     // [point][chan], stride 97
    __shared__ double dsq[64][4];
    int b = blockIdx.y;
    int n0 = blockIdx.x * 64;
    int tid = threadIdx.x;
    int n = tid & 63, w = tid >> 6;
    // read phase: wave w handles channel c = k*4 + w; yd/ftc coalesced 64-wide
    for (int k = 0; k < 24; ++k) {
        int c = k * 4 + w;
        size_t gi = ((size_t)b * C_ + c) * N_ + n0 + n;
        double m = stats[c * 2], rs = stats[c * 2 + 1];
        double v = (double)g[c] * (yd[gi] - m) * rs + (double)be[c];
        ftc[gi] = (float)v;
        tile[n * 97 + c] = v;
    }
    __syncthreads();
    // write phase: thread -> point p, quarter q (24 channels)
    int p = n, q = w;
    double vals[24];
    double s = 0.0;
    const double* lp = &tile[p * 97 + q * 24];
#pragma unroll
    for (int m2 = 0; m2 < 24; ++m2) { vals[m2] = lp[m2]; s += vals[m2] * vals[m2]; }
    dsq[p][q] = s;
    double* dst = ftp64 + ((size_t)b * N_ + n0 + p) * C_ + q * 24;   // tile is globally contiguous
#pragma unroll
    for (int m2 = 0; m2 < 24; m2 += 2) *(double2*)&dst[m2] = make_double2(vals[m2], vals[m2 + 1]);
    unsigned* hdst = (unsigned*)(fspH + ((size_t)b * N_ + n0 + p) * QS2);
#pragma unroll
    for (int m2 = 0; m2 < 24; m2 += 2) {
        unsigned u0 = __float_as_uint((float)vals[m2]);
        unsigned u1 = __float_as_uint((float)vals[m2 + 1]);
        unsigned h0 = (u0 + 0x7fffu + ((u0 >> 16) & 1u)) >> 16;      // RNE to bf16
        unsigned h1 = (u1 + 0x7fffu + ((u1 >> 16) & 1u)) >> 16;
        hdst[q * 12 + (m2 >> 1)] = h0 | (h1 << 16);
    }
    __syncthreads();
    if (tid < 64) {
        double tot = dsq[tid][0] + dsq[tid][1] + dsq[tid][2] + dsq[tid][3];
        sq64[(size_t)b * N_ + n0 + tid] = tot;
        sq32[(size_t)b * N_ + n0 + tid] = (float)tot;
    }
}

// ---------------- swapped-operand hi-bf16 MFMA distance, 2-pass t9 threshold + compaction ----------------
// block = 64 queries x all 3136 candidates (49 chunks of 64); 4 waves; XOR-swizzled LDS tiles;
// double-buffered chunk staging. Queries are staged into buf0 (reused for chunk 0 afterwards).
// pass 0: per-query chunk minima -> t9 (provable >=9 bound); pass 1: compact cands with
// d <= t9 + 1% + 1.0; fp64 re-rank restores exactness.
__global__ __launch_bounds__(256) void k_dist3(const unsigned short* __restrict__ fspH,
                                               const float* __restrict__ sq32,
                                               unsigned short* __restrict__ poolC,
                                               unsigned* __restrict__ poolCnt) {
    __shared__ __align__(16) char lds[48256];
    // buf0 [0,16384) | buf1 [16384,32768) | cminL [32768,39040) | poolL [39040,47232)
    // cntL [47232,47488) | t9fL [47488,47744) | sq tiles [47744,48256)
    unsigned short* cminL = (unsigned short*)(lds + 32768);
    unsigned short* poolL = (unsigned short*)(lds + 39040);
    unsigned*       cntL  = (unsigned*)(lds + 47232);
    float*          t9fL  = (float*)(lds + 47488);

    int b = blockIdx.y;
    int q0 = blockIdx.x * 64;
    int tid = threadIdx.x;
    int w = tid >> 6, l = tid & 63;

    // stage queries (64 x 256 B, swizzled) into buf0, then load query B-frags to registers
    {
        const uint4* src = (const uint4*)(fspH + ((size_t)b * N_ + q0) * QS2);
        uint4* dst = (uint4*)lds;
        for (int i = tid; i < 1024; i += 256) dst[swz16(i)] = src[i];
    }
    __syncthreads();
    bf16x8 Bq[3];
    {
        const unsigned short* Ql = (const unsigned short*)lds;
        int qr = w * 16 + (l & 15);
#pragma unroll
        for (int s = 0; s < 3; ++s) {
            int col = (s * 4 + (l >> 4)) ^ (qr & 7);
            Bq[s] = *(const bf16x8*)&Ql[qr * QS2 + col * 8];
        }
    }
    __syncthreads();   // queries now in registers; buf0 free

    // prologue: stage chunk 0 into buffer 0
    {
        const uint4* src = (const uint4*)(fspH + (size_t)b * N_ * QS2);
        uint4* dst = (uint4*)lds;
        for (int i = tid; i < 1024; i += 256) dst[swz16(i)] = src[i];
        if (tid < 64) ((float*)(lds + 47744))[tid] = sq32[(size_t)b * N_ + tid];
    }
    __syncthreads();

    float t9r = 0.f;
    int cur = 0;
    for (int t = 0; t < 98; ++t) {
        int ch = (t < 49) ? t : t - 49;
        int c0 = ch * 64;
        bool pf = (t < 97);
        uint4 st0, st1, st2, st3; float sqst = 0.f;
        if (pf) {
            int nch = (t + 1 < 49) ? (t + 1) : (t + 1 - 49);
            const uint4* src = (const uint4*)(fspH + ((size_t)b * N_ + nch * 64) * QS2);
            st0 = src[tid];
            st1 = src[tid + 256];
            st2 = src[tid + 512];
            st3 = src[tid + 768];
            if (tid < 64) sqst = sq32[(size_t)b * N_ + nch * 64 + tid];
        }
        // compute on current buffer
        const unsigned short* Bc = (const unsigned short*)(lds + cur * 16384);
        const float* sqc = (const float*)(lds + 47744 + cur * 256);
        f32x4 acc[4];
#pragma unroll
        for (int ct = 0; ct < 4; ++ct) acc[ct] = (f32x4){0.f, 0.f, 0.f, 0.f};
#pragma unroll
        for (int s = 0; s < 3; ++s) {
#pragma unroll
            for (int ct = 0; ct < 4; ++ct) {
                int cr = ct * 16 + (l & 15);
                int col = (s * 4 + (l >> 4)) ^ (cr & 7);
                bf16x8 Ac = *(const bf16x8*)&Bc[cr * QS2 + col * 8];
                acc[ct] = __builtin_amdgcn_mfma_f32_16x16x32_bf16(Ac, Bq[s], acc[ct], 0, 0, 0);
            }
        }
        f32x4 scn[4];
#pragma unroll
        for (int ct = 0; ct < 4; ++ct) scn[ct] = *(const f32x4*)&sqc[ct * 16 + (l >> 4) * 4];
        if (t < 49) {
            // per-query min over this chunk's 64 candidates (query-norm dropped: order-invariant)
            float m = 1e30f;
#pragma unroll
            for (int ct = 0; ct < 4; ++ct)
#pragma unroll
                for (int j = 0; j < 4; ++j)
                    m = fminf(m, fmaf(-2.f, acc[ct][j], scn[ct][j]));
            m = fminf(m, __shfl_xor(m, 16, 64));
            m = fminf(m, __shfl_xor(m, 32, 64));
            if (l < 16) {
                unsigned u = __float_as_uint(m);
                unsigned ku = u ^ (0x80000000u | (unsigned)((int)u >> 31));   // monotone key
                cminL[ch * 64 + w * 16 + l] = (unsigned short)(ku >> 16);
            }
        } else {
            int qrow = w * 16 + (l & 15);
#pragma unroll
            for (int ct = 0; ct < 4; ++ct)
#pragma unroll
                for (int j = 0; j < 4; ++j) {
                    float d = fmaf(-2.f, acc[ct][j], scn[ct][j]);
                    if (d <= t9r) {                                           // rare
                        unsigned pos = atomicAdd(&cntL[qrow], 1u);
                        if (pos < (unsigned)CAP3)
                            poolL[qrow * CAP3 + pos] = (unsigned short)(c0 + ct * 16 + (l >> 4) * 4 + j);
                    }
                }
        }
        if (t == 48) {
            __syncthreads();       // all cmin written
            if (tid < 64) {
                unsigned short top[9];
#pragma unroll
                for (int j = 0; j < 9; ++j) top[j] = 0xFFFFu;
                for (int q = 0; q < 49; ++q) {
                    unsigned short v = cminL[q * 64 + tid];
                    if (v < top[8]) {
                        top[8] = v;
#pragma unroll
                        for (int j = 8; j >= 1; --j)
                            if (top[j] < top[j - 1]) { unsigned short tt = top[j]; top[j] = top[j - 1]; top[j - 1] = tt; }
                    }
                }
                unsigned ku = ((unsigned)top[8] << 16) | 0xFFFFu;    // bucket upper bound
                float f = (ku & 0x80000000u) ? __uint_as_float(ku ^ 0x80000000u)
                                             : __uint_as_float(~ku);
                t9fL[tid] = f + fabsf(f) * 0.01f + 1.0f;             // safe hi-bf16 error inflation
                cntL[tid] = 0u;
            }
            __syncthreads();
            t9r = t9fL[w * 16 + (l & 15)];
        }
        if (pf) {
            uint4* dst = (uint4*)(lds + (cur ^ 1) * 16384);
            dst[swz16(tid)] = st0;
            dst[swz16(tid + 256)] = st1;
            dst[swz16(tid + 512)] = st2;
            dst[swz16(tid + 768)] = st3;
            if (tid < 64) ((float*)(lds + 47744 + (cur ^ 1) * 256))[tid] = sqst;
        }
        __syncthreads();
        cur ^= 1;
    }
    if (tid < 64) {
        unsigned c = cntL[tid];
        poolCnt[(size_t)b * N_ + q0 + tid] = (c > (unsigned)CAP3) ? (unsigned)CAP3 : c;
    }
    {
        unsigned* dst = (unsigned*)(poolC + ((size_t)b * N_ + q0) * CAP3);
        const unsigned* src = (const unsigned*)poolL;
        for (int i = tid; i < 64 * CAP3 / 2; i += 256) dst[i] = src[i];
    }
}

// ---------------- fp64 exact re-rank of variable pool -> top-9 set ----------------
// one wave per row; 16 candidates x 4 lanes per group, up to 4 groups; lexicographic extraction
__global__ __launch_bounds__(256) void k_rerank_d(const unsigned short* __restrict__ poolC,
                                                  const unsigned* __restrict__ poolCnt,
                                                  const double* __restrict__ ftp64,
                                                  const double* __restrict__ sq64,
                                                  int* __restrict__ idx) {
    int tid = threadIdx.x;
    int wv = tid >> 6, l = tid & 63;
    int rr = blockIdx.x * 4 + wv;
    int b = rr / N_;
    int cnt = (int)poolCnt[rr];
    if (cnt > CAP3) cnt = CAP3;
    int e = l & 3;
    // query segment in registers (24 doubles)
    double qreg[24];
    {
        const double* qb = ftp64 + (size_t)rr * C_ + e * 24;
#pragma unroll
        for (int m = 0; m < 24; ++m) qreg[m] = qb[m];
    }
    double dv[4];
    int jv[4];
#pragma unroll
    for (int gG = 0; gG < 4; ++gG) { dv[gG] = 1e300; jv[gG] = 0x7fffffff; }
#pragma unroll
    for (int gG = 0; gG < 4; ++gG) {
        if (gG * 16 >= cnt) break;                 // wave-uniform skip
        int ci = gG * 16 + (l >> 2);
        bool valid = ci < cnt;
        int j = valid ? (int)poolC[(size_t)rr * CAP3 + ci] : 0;
        const double* cb = ftp64 + ((size_t)b * N_ + j) * C_ + e * 24;
        double p = 0.0;
#pragma unroll
        for (int m = 0; m < 24; ++m) p += qreg[m] * cb[m];
        p += __shfl_xor(p, 1, 64);
        p += __shfl_xor(p, 2, 64);
        if (valid) {
            dv[gG] = sq64[(size_t)b * N_ + j] - 2.0 * p;   // per-row sqn dropped
            jv[gG] = j;
        }
    }
#pragma unroll
    for (int r = 0; r < 9; ++r) {
        double dm = dv[0]; int jm = jv[0];
#pragma unroll
        for (int gG = 1; gG < 4; ++gG)
            if (dv[gG] < dm || (dv[gG] == dm && jv[gG] < jm)) { dm = dv[gG]; jm = jv[gG]; }
#pragma unroll
        for (int off = 1; off <= 32; off <<= 1) {
            double od = __shfl_xor(dm, off, 64);
            int oj = __shfl_xor(jm, off, 64);
            if (od < dm || (od == dm && oj < jm)) { dm = od; jm = oj; }
        }
        if (l == 0) idx[(size_t)rr * 9 + r] = jm;
#pragma unroll
        for (int gG = 0; gG < 4; ++gG)
            if (jv[gG] == jm) dv[gG] = 1e300;      // retire winner (j unique)
    }
}

// ---------------- u = ft·(Wtop-Wbot) + b_edge (mode 0), v = ft·Wbot (mode 1) ----------------
__global__ __launch_bounds__(512) void k_gemm_uv(const float* __restrict__ ftc,
                                                 const float* __restrict__ We,
                                                 const float* __restrict__ beb,
                                                 float* __restrict__ out, int mode) {
    __shared__ float Wl[96 * 48];
    int tid = threadIdx.x;
    int rl = tid & 255, h = tid >> 8;
    int dbase = blockIdx.y * 48;
    for (int q = tid; q < 96 * 48; q += 512) {
        int c = q / 48, dd = q % 48;
        float w = We[(96 + c) * C2_ + dbase + dd];
        if (mode == 0) w = We[c * C2_ + dbase + dd] - w;
        Wl[c * 48 + dd] = w;
    }
    __syncthreads();
    int r = blockIdx.x * 256 + rl;
    int b = r / N_, n = r - b * N_;
    float acc[24];
#pragma unroll
    for (int i = 0; i < 24; i++) acc[i] = 0.f;
    const float* xp = ftc + (size_t)b * C_ * N_ + n;
    for (int c = 0; c < 96; ++c) {
        float xv = xp[(size_t)c * N_];
        const float4* w4 = (const float4*)&Wl[c * 48 + h * 24];
#pragma unroll
        for (int i = 0; i < 6; ++i) {
            float4 w = w4[i];
            acc[i * 4 + 0] += xv * w.x;
            acc[i * 4 + 1] += xv * w.y;
            acc[i * 4 + 2] += xv * w.z;
            acc[i * 4 + 3] += xv * w.w;
        }
    }
    int d0 = dbase + h * 24;
    float* op = out + (size_t)r * C2_ + d0;
#pragma unroll
    for (int i = 0; i < 6; ++i) {
        float4 o;
        o.x = acc[i * 4 + 0]; o.y = acc[i * 4 + 1];
        o.z = acc[i * 4 + 2]; o.w = acc[i * 4 + 3];
        if (mode == 0) {
            o.x += beb[d0 + i * 4 + 0];
            o.y += beb[d0 + i * 4 + 1];
            o.z += beb[d0 + i * 4 + 2];
            o.w += beb[d0 + i * 4 + 3];
        }
        ((float4*)op)[i] = o;
    }
}

// ---------------- edge-BN stats: e = u[n,d] + v[j,d] over all (row,k) ----------------
__global__ __launch_bounds__(192) void k_bne_stats(const float* __restrict__ u,
                                                   const float* __restrict__ v,
                                                   const int* __restrict__ idx,
                                                   float* __restrict__ partial) {
    int d = threadIdx.x;
    int row0 = blockIdx.x * 32;
    int b = row0 / N_;
    float s = 0.f, ss = 0.f;
    for (int r = 0; r < 32; ++r) {
        int row = row0 + r;
        float ud = u[(size_t)row * C2_ + d];
        const int* ip = idx + (size_t)row * 9;
#pragma unroll
        for (int k = 0; k < 9; k++) {
            int j = ip[k];
            float e = ud + v[((size_t)b * N_ + j) * C2_ + d];
            s += e;
            ss += e * e;
        }
    }
    partial[(size_t)blockIdx.x * 384 + d] = s;
    partial[(size_t)blockIdx.x * 384 + 192 + d] = ss;
}

// ---------------- edge BN+relu+max over k, then fc2 (192->96) ----------------
__global__ __launch_bounds__(192) void k_edge_fc2(const float* __restrict__ u,
                                                  const float* __restrict__ v,
                                                  const int* __restrict__ idx,
                                                  const float* __restrict__ statsE,
                                                  const float* __restrict__ ge,
                                                  const float* __restrict__ bee,
                                                  const float* __restrict__ W2,
                                                  const float* __restrict__ b2,
                                                  float* __restrict__ out2) {
    __shared__ float gl[16][C2_];
    __shared__ float g2[C_][16];
    int tid = threadIdx.x;
    int row0 = blockIdx.x * 16;
    int b = row0 / N_;
    int n0 = row0 - b * N_;
    {
        int d = tid;
        float m = statsE[d * 2], rs = statsE[d * 2 + 1];
        float ga = ge[d], bb = bee[d];
        for (int r = 0; r < 16; ++r) {
            int row = row0 + r;
            float ud = u[(size_t)row * C2_ + d];
            const int* ip = idx + (size_t)row * 9;
            float gm = 0.f;                      // relu-then-max == max with 0
#pragma unroll
            for (int k = 0; k < 9; k++) {
                int j = ip[k];
                float e = ud + v[((size_t)b * N_ + j) * C2_ + d];
                float val = ga * (e - m) * rs + bb;
                gm = fmaxf(gm, val);
            }
            gl[r][d] = gm;
        }
    }
    __syncthreads();
    {
        int rr = tid / 24;
        int dq = tid % 24;
        for (int rep = 0; rep < 2; ++rep) {
            int r = rr + rep * 8;
            float4 acc = *(const float4*)&b2[dq * 4];
            for (int d = 0; d < C2_; ++d) {
                float gv = gl[r][d];
                float4 w = *(const float4*)&W2[d * C_ + dq * 4];
                acc.x += gv * w.x;
                acc.y += gv * w.y;
                acc.z += gv * w.z;
                acc.w += gv * w.w;
            }
            g2[dq * 4 + 0][r] = acc.x;
            g2[dq * 4 + 1][r] = acc.y;
            g2[dq * 4 + 2][r] = acc.z;
            g2[dq * 4 + 3][r] = acc.w;
        }
    }
    __syncthreads();
    for (int q = tid; q < 96 * 4; q += 192) {
        int dd = q / 4, part = q % 4;
        float4 val = *(const float4*)&g2[dd][part * 4];
        *(float4*)&out2[((size_t)b * C_ + dd) * N_ + n0 + part * 4] = val;
    }
}

// ---------------- t = bn2(out2) + x, with fused per-channel stats of t (for sabn) ----------------
__global__ __launch_bounds__(256) void k_bn2_add_st(const float* __restrict__ out2,
                                                    const float* __restrict__ x,
                                                    const float* __restrict__ stats,
                                                    const float* __restrict__ g,
                                                    const float* __restrict__ be,
                                                    float* __restrict__ t,
                                                    float* __restrict__ partial) {
    int c = blockIdx.x;
    int chunk = blockIdx.y;
    const int SPLIT = 16;
    float m = stats[c * 2], rs = stats[c * 2 + 1];
    float ga = g[c], bb = be[c];
    float s = 0.f, ss = 0.f;
    for (int j = chunk * 256 + threadIdx.x; j < R_; j += SPLIT * 256) {
        int b = j / N_, n = j - b * N_;
        size_t i = ((size_t)b * C_ + c) * N_ + n;
        float tv = ga * (out2[i] - m) * rs + bb + x[i];
        t[i] = tv;
        s += tv;
        ss += tv * tv;
    }
    __shared__ float red[8];
    for (int off = 32; off; off >>= 1) {
        s += __shfl_down(s, off, 64);
        ss += __shfl_down(ss, off, 64);
    }
    int lane = threadIdx.x & 63, w = threadIdx.x >> 6;
    if (lane == 0) { red[w * 2] = s; red[w * 2 + 1] = ss; }
    __syncthreads();
    if (threadIdx.x == 0) {
        s = red[0] + red[2] + red[4] + red[6];
        ss = red[1] + red[3] + red[5] + red[7];
        partial[(c * SPLIT + chunk) * 2] = s;
        partial[(c * SPLIT + chunk) * 2 + 1] = ss;
    }
}

// ---------------- s = relu(sabn(t)) ----------------
__global__ __launch_bounds__(256) void k_sabn_relu(const float* __restrict__ t,
                                                   const float* __restrict__ stats,
                                                   const float* __restrict__ g,
                                                   const float* __restrict__ be,
                                                   float* __restrict__ s) {
    int i = blockIdx.x * 256 + threadIdx.x;
    if (i >= B_ * C_ * N_) return;
    int c = (i / N_) % C_;
    s[i] = fmaxf(g[c] * (t[i] - stats[c * 2]) * stats[c * 2 + 1] + be[c], 0.f);
}

// ---------------- conv 3x3 stride 2 pad 1, 96->192 ----------------
__global__ __launch_bounds__(256) void k_conv(const float* __restrict__ s,
                                              const float* __restrict__ Wd,
                                              const float* __restrict__ bd,
                                              float* __restrict__ z) {
    __shared__ float Wl[96 * 9 * 16];
    int b = blockIdx.z;
    int oc0 = blockIdx.y * 16;
    int p = blockIdx.x * 256 + threadIdx.x;
    for (int i = threadIdx.x; i < 96 * 9 * 16; i += 256) {
        int oc = i & 15;
        int icq = i >> 4;
        Wl[i] = Wd[(size_t)(oc0 + oc) * 864 + icq];
    }
    __syncthreads();
    if (p >= NO_) return;
    int oh = p / HO_, ow = p % HO_;
    float acc[16];
#pragma unroll
    for (int i = 0; i < 16; i++) acc[i] = 0.f;
    int ih0 = oh * 2 - 1, iw0 = ow * 2 - 1;
    const float* sb = s + (size_t)b * C_ * N_;
    for (int ic = 0; ic < 96; ++ic) {
        const float* sp = sb + (size_t)ic * N_;
        float in[9];
#pragma unroll
        for (int kh = 0; kh < 3; kh++) {
            int ih = ih0 + kh;
            bool okh = (unsigned)ih < 56u;
#pragma unroll
            for (int kw = 0; kw < 3; kw++) {
                int iw = iw0 + kw;
                bool ok = okh && ((unsigned)iw < 56u);
                in[kh * 3 + kw] = ok ? sp[ih * 56 + iw] : 0.f;
            }
        }
#pragma unroll
        for (int q = 0; q < 9; q++) {
            float iv = in[q];
            const float4* w4 = (const float4*)&Wl[(ic * 9 + q) * 16];
#pragma unroll
            for (int j = 0; j < 4; j++) {
                float4 w = w4[j];
                acc[j * 4 + 0] += iv * w.x;
                acc[j * 4 + 1] += iv * w.y;
                acc[j * 4 + 2] += iv * w.z;
                acc[j * 4 + 3] += iv * w.w;
            }
        }
    }
#pragma unroll
    for (int i = 0; i < 16; i++)
        z[((size_t)b * OUP_ + oc0 + i) * NO_ + p] = acc[i] + bd[oc0 + i];
}

// ---------------- out = relu(dwbn(z)) ----------------
__global__ __launch_bounds__(256) void k_out(const float* __restrict__ z,
                                             const float* __restrict__ stats,
                                             const float* __restrict__ g,
                                             const float* __restrict__ be,
                                             float* __restrict__ out) {
    int i = blockIdx.x * 256 + threadIdx.x;
    if (i >= B_ * OUP_ * NO_) return;
    int c = (i / NO_) % OUP_;
    out[i] = fmaxf(g[c] * (z[i] - stats[c * 2]) * stats[c * 2 + 1] + be[c], 0.f);
}

extern "C" void kernel_launch(void* const* d_in, const int* in_sizes, int n_in,
                              void* d_out, int out_size, void* d_ws, size_t ws_size,
                              hipStream_t stream) {
    const float* x     = (const float*)d_in[0];
    const float* W_fc1 = (const float*)d_in[1];
    const float* b_fc1 = (const float*)d_in[2];
    const float* g_bn1 = (const float*)d_in[3];
    const float* be_bn1= (const float*)d_in[4];
    const float* W_edge= (const float*)d_in[5];
    const float* b_edge= (const float*)d_in[6];
    const float* g_bne = (const float*)d_in[7];
    const float* be_bne= (const float*)d_in[8];
    const float* W_fc2 = (const float*)d_in[9];
    const float* b_fc2 = (const float*)d_in[10];
    const float* g_bn2 = (const float*)d_in[11];
    const float* be_bn2= (const float*)d_in[12];
    const float* g_sabn= (const float*)d_in[13];
    const float* be_sabn=(const float*)d_in[14];
    const float* W_dw  = (const float*)d_in[15];
    const float* b_dw  = (const float*)d_in[16];
    const float* g_dwbn= (const float*)d_in[17];
    const float* be_dwbn=(const float*)d_in[18];

    // byte-offset workspace layout with lifetime-based aliasing (~74.8 MB)
    char* base = (char*)d_ws;
    float*  ftc   = (float*)(base + 0);                    //  9,633,792 [bn1_tr -> gemm_uv]; then sbuf
    float*  sbuf  = (float*)(base + 0);
    double* ftp64 = (double*)(base + 9633792);             // 19,267,584 [bn1_tr -> rerank]; then uu
    float*  uu    = (float*)(base + 9633792);
    double* yd    = (double*)(base + 28901376);            // 19,267,584 [fc1 -> bn1_tr]; then vv
    float*  vv    = (float*)(base + 28901376);
    unsigned short* fspH = (unsigned short*)(base + 48168960); // 6,422,528 [bn1_tr -> dist3]; then out2
    float*  out2  = (float*)(base + 48168960);             //  9,633,792 [edge_fc2 -> bn2]
    unsigned short* poolC = (unsigned short*)(base + 57802752); // 3,211,264 [dist3 -> rerank]; then tbuf
    float*  tbuf  = (float*)(base + 57802752);             //  9,633,792 [bn2 -> sabn]
    double* sq64  = (double*)(base + 67436544);            //    200,704
    int*    idx   = (int*)(base + 67637248);               //    903,168 [rerank -> edge]
    unsigned* poolCnt = (unsigned*)(base + 68540416);      //    100,352
    float*  sq32  = (float*)(base + 68640768);             //    100,352
    float*  partial = (float*)(base + 68741120);           //  1,204,224 max
    double* partiald = (double*)(base + 68741120);         //     24,576 (earlier use, same region)
    double* stats1d = (double*)(base + 69945344);          //      1,536
    float*  statsE  = (float*)(base + 69946880);
    float*  stats2  = (float*)(base + 69948416);
    float*  statsS  = (float*)(base + 69949952);
    float*  statsD  = (float*)(base + 69951488);
    float*  zbuf  = (float*)(base + 69953024);             //  4,816,896 [conv -> out] -> ends 74,769,920

    // fc1 + BN1 (fp64 path, exact stats + features); bn1_tr fuses apply+transpose+split+sqrows
    k_fc1_d<<<dim3(98, 2), 512, 0, stream>>>(x, W_fc1, b_fc1, yd);
    k_stats_chan_d<<<dim3(96, 16), 256, 0, stream>>>(yd, partiald);
    k_stats_reduce_d<<<1, 256, 0, stream>>>(partiald, stats1d);
    k_bn1_tr<<<dim3(49, B_), 256, 0, stream>>>(yd, stats1d, g_bn1, be_bn1, ftc, ftp64, fspH, sq64, sq32);

    // kNN: swapped-operand hi-bf16 MFMA (swizzled LDS) + t9 threshold/compaction, fp64 re-rank
    k_dist3<<<dim3(49, B_), 256, 0, stream>>>(fspH, sq32, poolC, poolCnt);
    k_rerank_d<<<6272, 256, 0, stream>>>(poolC, poolCnt, ftp64, sq64, idx);

    // edge GEMM decomposition: u = ft·(Wtop-Wbot)+b_edge, v = ft·Wbot (uu/vv overwrite ftp64/yd)
    k_gemm_uv<<<dim3(98, 4), 512, 0, stream>>>(ftc, W_edge, b_edge, uu, 0);
    k_gemm_uv<<<dim3(98, 4), 512, 0, stream>>>(ftc, W_edge, b_edge, vv, 1);

    // edge BN stats, then BN+relu+max+fc2
    k_bne_stats<<<784, 192, 0, stream>>>(uu, vv, idx, partial);
    k_stats_reduce_b2<<<192, 256, 0, stream>>>(partial, statsE, 1.0f / 225792.0f);
    k_edge_fc2<<<1568, 192, 0, stream>>>(uu, vv, idx, statsE, g_bne, be_bne, W_fc2, b_fc2, out2);

    // BN2 + shortcut (stats of t fused into the add pass)
    k_stats_chan<<<dim3(96, 16), 256, 0, stream>>>(out2, partial, 96, N_, R_);
    k_stats_reduce<<<1, 256, 0, stream>>>(partial, stats2, 96, 16, 1.0f / (float)R_);
    k_bn2_add_st<<<dim3(96, 16), 256, 0, stream>>>(out2, x, stats2, g_bn2, be_bn2, tbuf, partial);
    k_stats_reduce<<<1, 256, 0, stream>>>(partial, statsS, 96, 16, 1.0f / (float)R_);
    k_sabn_relu<<<9408, 256, 0, stream>>>(tbuf, statsS, g_sabn, be_sabn, sbuf);

    // conv + dwbn + relu
    k_conv<<<dim3(4, 12, 8), 256, 0, stream>>>(sbuf, W_dw, b_dw, zbuf);
    k_stats_chan<<<dim3(192, 8), 256, 0, stream>>>(zbuf, partial, 192, NO_, 6272);
    k_stats_reduce<<<1, 256, 0, stream>>>(partial, statsD, 192, 8, 1.0f / 6272.0f);
    k_out<<<4705, 256, 0, stream>>>(zbuf, statsD, g_dwbn, be_dwbn, (float*)d_out);
}